// Round 6
// baseline (3550.113 us; speedup 1.0000x reference)
//
#include <hip/hip_runtime.h>
#include <cstdint>
#include <cstddef>

// GPT-12-layer forward, bf16 MFMA pipeline.
//   activations: rows = b*512 + l  (M = 8192), row-major, f32 residual + bf16 copy
//   weights: pre-transposed per layer to Wt[N][K] bf16
// Big-N GEMMs (qkv N=2304, fc N=3072): 8-phase 256x256 template, 512 thr,
//   8 waves (2Mx4N, 128x64/wave), BK=64, 128KiB LDS dbuf, staggered half-tile
//   staging, ONE counted vmcnt(4) per K-tile (never 0 mid-loop), setprio MFMA.
// N=768 GEMMs (proj, mlp): R2-proven 2-phase 128x64 tile, BK=64, bf16 out.
// Attention: flash-style as before. LN: wave-per-row, vectorized, reads bf16
//   GEMM-out + f32 residual.

#define LSEQ 512
#define NBATCH 16
#define EDIM 768
#define NHEAD 12
#define NLAYER 12

typedef __attribute__((ext_vector_type(8))) short short8;
typedef __attribute__((ext_vector_type(4))) short short4v;
typedef __attribute__((ext_vector_type(4))) float f32x4;

__device__ __forceinline__ short f2bf(float f) {
  union { float f; unsigned u; } x; x.f = f;
  return (short)((x.u + 0x7FFFu + ((x.u >> 16) & 1u)) >> 16);  // RNE
}
__device__ __forceinline__ float bf2f(short s) {
  union { unsigned u; float f; } x; x.u = ((unsigned)(unsigned short)s) << 16;
  return x.f;
}

__device__ __forceinline__ void gload_lds16(const void* g, void* l) {
  __builtin_amdgcn_global_load_lds(
      (__attribute__((address_space(1))) void*)(void*)g,
      (__attribute__((address_space(3))) void*)l, 16, 0, 0);
}

// ---------------- weight transpose + bf16 convert: W[K][N] f32 -> Wt[N][K] bf16
__global__ __launch_bounds__(256) void wt_transpose(const float* __restrict__ W,
                                                    short* __restrict__ Wt,
                                                    int K, int N) {
  __shared__ float tile[32][33];
  const int n0 = blockIdx.x * 32, k0 = blockIdx.y * 32;
  const size_t lo = (size_t)blockIdx.z * K * N;
  const float* Ws = W + lo;
  short* Wd = Wt + lo;
  const int tx = threadIdx.x & 31, ty = threadIdx.x >> 5;  // 32 x 8
#pragma unroll
  for (int i = 0; i < 4; ++i)
    tile[ty + i * 8][tx] = Ws[(size_t)(k0 + ty + i * 8) * N + n0 + tx];
  __syncthreads();
#pragma unroll
  for (int i = 0; i < 4; ++i)
    Wd[(size_t)(n0 + ty + i * 8) * K + k0 + tx] = f2bf(tile[tx][ty + i * 8]);
}

// ---------------- embed: h[b*L+l][e] = x[l][b][e] + pos[l][e]
__global__ __launch_bounds__(256) void embed_k(const float* __restrict__ x,
                                               const float* __restrict__ pos,
                                               float* __restrict__ h,
                                               short* __restrict__ hbf) {
  const int row = blockIdx.x;  // b*512 + l
  const int b = row >> 9, lp = row & 511;
  const int t = threadIdx.x;
#pragma unroll
  for (int i = 0; i < 3; ++i) {
    const int e = t + i * 256;
    float v = x[(size_t)(lp * 16 + b) * 768 + e] + pos[(size_t)lp * 768 + e];
    h[(size_t)row * 768 + e] = v;
    hbf[(size_t)row * 768 + e] = f2bf(v);
  }
}

// ---------------- final: out[l][b][e] = h[b*L+l][e]
__global__ __launch_bounds__(256) void final_k(const float* __restrict__ h,
                                               float* __restrict__ out) {
  const int row = blockIdx.x;  // l*16 + b
  const int lp = row >> 4, b = row & 15;
  const int t = threadIdx.x;
#pragma unroll
  for (int i = 0; i < 3; ++i) {
    const int e = t + i * 256;
    out[(size_t)row * 768 + e] = h[(size_t)(b * 512 + lp) * 768 + e];
  }
}

// ---------------- fused residual-add + LayerNorm, wave-per-row
// A: f32 residual, B: bf16 gemm-out; writes f32 residual + bf16 copy
__global__ __launch_bounds__(256) void ln_fused(const float* __restrict__ A,
                                                const short* __restrict__ B,
                                                const float* __restrict__ g,
                                                const float* __restrict__ be,
                                                float* __restrict__ outf,
                                                short* __restrict__ outb) {
  const int row = blockIdx.x * 4 + (threadIdx.x >> 6);
  const int l = threadIdx.x & 63;
  const size_t base = (size_t)row * 768;
  float v[12];
  float s1 = 0.f, s2 = 0.f;
#pragma unroll
  for (int j = 0; j < 3; ++j) {
    const int e = j * 256 + l * 4;
    f32x4 a = *(const f32x4*)&A[base + e];
    short4v b = *(const short4v*)&B[base + e];
#pragma unroll
    for (int q = 0; q < 4; ++q) {
      float x = a[q] + bf2f(b[q]);
      v[j * 4 + q] = x; s1 += x; s2 += x * x;
    }
  }
#pragma unroll
  for (int m = 1; m < 64; m <<= 1) {
    s1 += __shfl_xor(s1, m);
    s2 += __shfl_xor(s2, m);
  }
  const float mu = s1 * (1.f / 768.f);
  const float rs = rsqrtf(s2 * (1.f / 768.f) - mu * mu + 1e-5f);
#pragma unroll
  for (int j = 0; j < 3; ++j) {
    const int e = j * 256 + l * 4;
    f32x4 gv = *(const f32x4*)&g[e];
    f32x4 bv = *(const f32x4*)&be[e];
    f32x4 of; short4v ob;
#pragma unroll
    for (int q = 0; q < 4; ++q) {
      float o = (v[j * 4 + q] - mu) * rs * gv[q] + bv[q];
      of[q] = o; ob[q] = f2bf(o);
    }
    *(f32x4*)&outf[base + e] = of;
    *(short4v*)&outb[base + e] = ob;
  }
}

// ---------------- 8-phase 256x256 GEMM (qkv, fc): C = A * Bt^T + bias
// 512 threads, 8 waves 2Mx4N (128x64 per wave), BK=64, 128 KiB LDS.
// EPI: 1 = bf16 out, 2 = gelu(bf16) out
template <int EPI>
__global__ __launch_bounds__(512, 1) void gemm8(const short* __restrict__ A,
                                                const short* __restrict__ Bt,
                                                const float* __restrict__ bias,
                                                short* __restrict__ C,
                                                int N, int K) {
  __shared__ alignas(16) short Ab[2][256 * 64];
  __shared__ alignas(16) short Bb[2][256 * 64];
  const int t = threadIdx.x;
  const int w = t >> 6, l = t & 63;
  const int wr = w >> 2, wc = w & 3;            // wave grid 2M x 4N
  const int l15 = l & 15, lhi = l >> 4;
  const int rowA0 = blockIdx.x * 256;
  const int rowB0 = blockIdx.y * 256;
  const int nk = K >> 6;
  const int sr = l >> 3, sl = l & 7;            // staging row-in-chunk / slot

  f32x4 acc[8][4];
#pragma unroll
  for (int a = 0; a < 8; ++a)
#pragma unroll
    for (int b = 0; b < 4; ++b) acc[a][b] = (f32x4){0.f, 0.f, 0.f, 0.f};

  // stage one 128-row half of a K-tile (2 x gload_lds per thread).
  // LDS dest linear; global source pre-swizzled: slot ^= (row&7).
  auto stageA = [&](int buf, int tile, int half) {
#pragma unroll
    for (int i = 0; i < 2; ++i) {
      const int rb = half * 128 + (i * 8 + w) * 8;   // 8-row chunk base
      const int r = rb + sr;
      gload_lds16(A + (size_t)(rowA0 + r) * K + tile * 64 + ((sl ^ (r & 7)) << 3),
                  &Ab[buf][rb * 64]);
    }
  };
  auto stageB = [&](int buf, int tile, int half) {
#pragma unroll
    for (int i = 0; i < 2; ++i) {
      const int rb = half * 128 + (i * 8 + w) * 8;
      const int r = rb + sr;
      gload_lds16(Bt + (size_t)(rowB0 + r) * K + tile * 64 + ((sl ^ (r & 7)) << 3),
                  &Bb[buf][rb * 64]);
    }
  };

  // prologue: tile0 (8 loads) + B(1) (4 loads); tile0 certified, B(1) in flight
  stageA(0, 0, 0); stageA(0, 0, 1);
  stageB(0, 0, 0); stageB(0, 0, 1);
  if (nk > 1) { stageB(1, 1, 0); stageB(1, 1, 1); }
  asm volatile("s_waitcnt vmcnt(4)" ::: "memory");
  __builtin_amdgcn_s_barrier();

  short8 bfr[4][2];
  for (int U = 0; U < nk; ++U) {
    const int cur = U & 1, nxt = cur ^ 1;
#pragma unroll
    for (int p = 0; p < 4; ++p) {
      // ds-load register subtile: A quad p (4 reads); +B all (8 reads) at p0
      short8 af[2][2];
#pragma unroll
      for (int rt = 0; rt < 2; ++rt)
#pragma unroll
        for (int kc = 0; kc < 2; ++kc) {
          const int r = wr * 128 + p * 32 + rt * 16 + l15;
          af[rt][kc] = *(const short8*)
              &Ab[cur][r * 64 + ((((kc << 2) | lhi) ^ (r & 7)) << 3)];
        }
      if (p == 0) {
#pragma unroll
        for (int ct = 0; ct < 4; ++ct)
#pragma unroll
          for (int kc = 0; kc < 2; ++kc) {
            const int r = wc * 64 + ct * 16 + l15;
            bfr[ct][kc] = *(const short8*)
                &Bb[cur][r * 64 + ((((kc << 2) | lhi) ^ (r & 7)) << 3)];
          }
      }
      // staggered half-tile prefetch:
      //   p0/p1: A(U+1) -> idle buffer (its last reads ended at tile U-1)
      //   p2/p3: B(U+2) -> current buffer's B region (released at p0)
      if (p == 0 && U + 1 < nk) stageA(nxt, U + 1, 0);
      if (p == 1 && U + 1 < nk) stageA(nxt, U + 1, 1);
      if (p == 2 && U + 2 < nk) stageB(cur, U + 2, 0);
      if (p == 3 && U + 2 < nk) stageB(cur, U + 2, 1);
      if (p == 3) {  // gate tile U+1 readiness; keep B(U+2) in flight
        if (U + 2 < nk) asm volatile("s_waitcnt vmcnt(4)" ::: "memory");
        else            asm volatile("s_waitcnt vmcnt(0)" ::: "memory");
      }
      __builtin_amdgcn_s_barrier();
      asm volatile("s_waitcnt lgkmcnt(0)" ::: "memory");
      __builtin_amdgcn_sched_barrier(0);
      __builtin_amdgcn_s_setprio(1);
#pragma unroll
      for (int rt = 0; rt < 2; ++rt)
#pragma unroll
        for (int ct = 0; ct < 4; ++ct)
#pragma unroll
          for (int kc = 0; kc < 2; ++kc)
            acc[p * 2 + rt][ct] = __builtin_amdgcn_mfma_f32_16x16x32_bf16(
                af[rt][kc], bfr[ct][kc], acc[p * 2 + rt][ct], 0, 0, 0);
      __builtin_amdgcn_s_setprio(0);
      __builtin_amdgcn_s_barrier();
    }
  }

  float bv[4];
#pragma unroll
  for (int ct = 0; ct < 4; ++ct) bv[ct] = bias[rowB0 + wc * 64 + ct * 16 + l15];
#pragma unroll
  for (int rt = 0; rt < 8; ++rt) {
#pragma unroll
    for (int ct = 0; ct < 4; ++ct) {
      const int col = rowB0 + wc * 64 + ct * 16 + l15;
#pragma unroll
      for (int i = 0; i < 4; ++i) {
        const int row = rowA0 + wr * 128 + rt * 16 + lhi * 4 + i;
        float v = acc[rt][ct][i] + bv[ct];
        if constexpr (EPI == 1) {
          C[(size_t)row * N + col] = f2bf(v);
        } else {
          // gelu_new via sigmoid: 0.5x(1+tanh z) = x / (1 + exp(-2z))
          float pz = v * fmaf(0.044715f, v * v, 1.0f);
          float e = __expf(-1.5957691216057308f * pz);
          float r = __builtin_amdgcn_rcpf(1.0f + e);
          C[(size_t)row * N + col] = f2bf(v * r);
        }
      }
    }
  }
}

// ---------------- 2-phase GEMM for N=768 (proj, mlp): 128x64 tile, BK=64
// (R2-proven structure). EPI: 1 = bf16 out
template <int TN, int EPI>
__global__ __launch_bounds__(256) void gemm_bt(const short* __restrict__ A,
                                               const short* __restrict__ Bt,
                                               const float* __restrict__ bias,
                                               void* __restrict__ C,
                                               int N, int K) {
  constexpr int BK = 64;
  __shared__ alignas(16) short Alds[128 * BK];
  __shared__ alignas(16) short Blds[TN * BK];
  const int t = threadIdx.x;
  const int w = t >> 6, l = t & 63;
  constexpr int WR = (TN == 128) ? 2 : 4;
  constexpr int WC = (TN == 128) ? 2 : 1;
  constexpr int WM = 128 / WR;
  constexpr int MI = WM / 16;
  constexpr int NI = (TN / WC) / 16;
  const int wr = (WC == 2) ? (w >> 1) : w;
  const int wc = (WC == 2) ? (w & 1) : 0;
  const int l15 = l & 15, lhi = l >> 4;
  const int rowA0 = blockIdx.x * 128;
  const int rowB0 = blockIdx.y * TN;
  f32x4 acc[MI][NI];
#pragma unroll
  for (int mi = 0; mi < MI; ++mi)
#pragma unroll
    for (int ni = 0; ni < NI; ++ni) acc[mi][ni] = (f32x4){0.f, 0.f, 0.f, 0.f};

  const int srl = l >> 3;
  const int ss = l & 7;

  for (int kt = 0; kt < K; kt += BK) {
#pragma unroll
    for (int i = 0; i < 4; ++i) {
      const int r = i * 32 + w * 8 + srl;
      gload_lds16(A + (size_t)(rowA0 + r) * K + kt + ((ss ^ (r & 7)) << 3),
                  &Alds[i * 2048 + w * 512]);
    }
#pragma unroll
    for (int i = 0; i < TN / 32; ++i) {
      const int r = i * 32 + w * 8 + srl;
      gload_lds16(Bt + (size_t)(rowB0 + r) * K + kt + ((ss ^ (r & 7)) << 3),
                  &Blds[i * 2048 + w * 512]);
    }
    __syncthreads();
    short8 af[MI][2], bfr[NI][2];
#pragma unroll
    for (int mi = 0; mi < MI; ++mi) {
      const int r = wr * WM + mi * 16 + l15;
#pragma unroll
      for (int kc = 0; kc < 2; ++kc)
        af[mi][kc] = *(const short8*)
            &Alds[r * 64 + ((((kc << 2) | lhi) ^ (r & 7)) << 3)];
    }
#pragma unroll
    for (int ni = 0; ni < NI; ++ni) {
      const int r = wc * 64 + ni * 16 + l15;
#pragma unroll
      for (int kc = 0; kc < 2; ++kc)
        bfr[ni][kc] = *(const short8*)
            &Blds[r * 64 + ((((kc << 2) | lhi) ^ (r & 7)) << 3)];
    }
#pragma unroll
    for (int mi = 0; mi < MI; ++mi)
#pragma unroll
      for (int ni = 0; ni < NI; ++ni)
#pragma unroll
        for (int kc = 0; kc < 2; ++kc)
          acc[mi][ni] = __builtin_amdgcn_mfma_f32_16x16x32_bf16(
              af[mi][kc], bfr[ni][kc], acc[mi][ni], 0, 0, 0);
    __syncthreads();
  }

  float bv[NI];
#pragma unroll
  for (int ni = 0; ni < NI; ++ni) bv[ni] = bias[rowB0 + wc * 64 + ni * 16 + l15];
#pragma unroll
  for (int mi = 0; mi < MI; ++mi) {
#pragma unroll
    for (int ni = 0; ni < NI; ++ni) {
      const int col = rowB0 + wc * 64 + ni * 16 + l15;
#pragma unroll
      for (int i = 0; i < 4; ++i) {
        const int row = rowA0 + wr * WM + mi * 16 + lhi * 4 + i;
        float v = acc[mi][ni][i] + bv[ni];
        if constexpr (EPI == 0) {
          ((float*)C)[(size_t)row * N + col] = v;
        } else {
          ((short*)C)[(size_t)row * N + col] = f2bf(v);
        }
      }
    }
  }
}

// ---------------- flash attention: block = (qb, head, batch), 4 waves
__global__ __launch_bounds__(256) void attn_k(const short* __restrict__ qkv,
                                              const float* __restrict__ mask,
                                              short* __restrict__ o) {
  const int qb = blockIdx.x;
  const int hh = blockIdx.y;
  const int b = blockIdx.z;
  const int t = threadIdx.x, w = t >> 6, l = t & 63;
  const int l15 = l & 15, lhi = l >> 4;
  __shared__ alignas(16) short Klds[64 * 64];
  __shared__ alignas(16) short Vlds[64 * 64];   // stored transposed: Vt[n][k]
  __shared__ alignas(16) short Plds[4][16 * 72];

  short8 qa[2];
  {
    const size_t base =
        (size_t)(b * LSEQ + qb * 64 + w * 16 + l15) * 2304 + hh * 64;
    qa[0] = *(const short8*)&qkv[base + lhi * 8];
    qa[1] = *(const short8*)&qkv[base + 32 + lhi * 8];
  }
  float mrow[4] = {-1e30f, -1e30f, -1e30f, -1e30f};
  float lrow[4] = {0.f, 0.f, 0.f, 0.f};
  const f32x4 zero4 = {0.f, 0.f, 0.f, 0.f};
  f32x4 oacc[4];
#pragma unroll
  for (int nt = 0; nt < 4; ++nt) oacc[nt] = zero4;

  const int nkt = qb + 1;
  for (int kt = 0; kt < nkt; ++kt) {
    __syncthreads();
    {
      const int kr = t >> 2, cc = (t & 3) * 16;
      const size_t grow = (size_t)(b * LSEQ + kt * 64 + kr) * 2304 + hh * 64;
      short8 k0 = *(const short8*)&qkv[grow + 768 + cc];
      short8 k1 = *(const short8*)&qkv[grow + 768 + cc + 8];
      short8 v0 = *(const short8*)&qkv[grow + 1536 + cc];
      short8 v1 = *(const short8*)&qkv[grow + 1536 + cc + 8];
      const int sw = (kr & 7) << 4;
      *(short8*)((char*)Klds + ((kr * 128 + cc * 2) ^ sw)) = k0;
      *(short8*)((char*)Klds + ((kr * 128 + cc * 2 + 16) ^ sw)) = k1;
#pragma unroll
      for (int e = 0; e < 8; ++e) {
        const int n0 = cc + e, n1 = cc + 8 + e;
        ((short*)Vlds)[((n0 * 128 + kr * 2) ^ ((n0 & 7) << 4)) >> 1] = v0[e];
        ((short*)Vlds)[((n1 * 128 + kr * 2) ^ ((n1 & 7) << 4)) >> 1] = v1[e];
      }
    }
    __syncthreads();

    f32x4 s[4];
#pragma unroll
    for (int jt = 0; jt < 4; ++jt) {
      f32x4 z = zero4;
#pragma unroll
      for (int kc = 0; kc < 2; ++kc) {
        const int rowk = jt * 16 + l15;
        short8 kb = *(const short8*)((char*)Klds +
                     ((rowk * 128 + kc * 64 + lhi * 16) ^ ((rowk & 7) << 4)));
        z = __builtin_amdgcn_mfma_f32_16x16x32_bf16(qa[kc], kb, z, 0, 0, 0);
      }
      s[jt] = z;
    }

    float addm[4];
#pragma unroll
    for (int jt = 0; jt < 4; ++jt)
      addm[jt] = (1.0f - mask[b * LSEQ + kt * 64 + jt * 16 + l15]) *
                 -3.402823466e38f;
#pragma unroll
    for (int jt = 0; jt < 4; ++jt) {
      const int colg = kt * 64 + jt * 16 + l15;
#pragma unroll
      for (int i = 0; i < 4; ++i) {
        const int rowg = qb * 64 + w * 16 + lhi * 4 + i;
        float sv = s[jt][i] * 0.125f;
        if (colg > rowg) sv = -10000.0f;
        s[jt][i] = sv + addm[jt];
      }
    }

    float mnew[4], sc[4];
#pragma unroll
    for (int i = 0; i < 4; ++i) {
      float tm = fmaxf(fmaxf(s[0][i], s[1][i]), fmaxf(s[2][i], s[3][i]));
#pragma unroll
      for (int mm = 1; mm < 16; mm <<= 1) tm = fmaxf(tm, __shfl_xor(tm, mm));
      mnew[i] = fmaxf(mrow[i], tm);
      sc[i] = __expf(mrow[i] - mnew[i]);
      mrow[i] = mnew[i];
    }
#pragma unroll
    for (int i = 0; i < 4; ++i) {
      float ts = 0.f;
#pragma unroll
      for (int jt = 0; jt < 4; ++jt) {
        float p = __expf(s[jt][i] - mnew[i]);
        s[jt][i] = p;
        ts += p;
      }
#pragma unroll
      for (int mm = 1; mm < 16; mm <<= 1) ts += __shfl_xor(ts, mm);
      lrow[i] = lrow[i] * sc[i] + ts;
      oacc[0][i] *= sc[i]; oacc[1][i] *= sc[i];
      oacc[2][i] *= sc[i]; oacc[3][i] *= sc[i];
    }

    short* Pw = &Plds[w][0];
#pragma unroll
    for (int jt = 0; jt < 4; ++jt)
#pragma unroll
      for (int i = 0; i < 4; ++i)
        Pw[(lhi * 4 + i) * 72 + jt * 16 + l15] = f2bf(s[jt][i]);
    __syncthreads();
    short8 pa[2];
#pragma unroll
    for (int kc = 0; kc < 2; ++kc)
      pa[kc] = *(const short8*)&Pw[l15 * 72 + kc * 32 + lhi * 8];

#pragma unroll
    for (int nt = 0; nt < 4; ++nt) {
#pragma unroll
      for (int kc = 0; kc < 2; ++kc) {
        const int rown = nt * 16 + l15;
        short8 vb = *(const short8*)((char*)Vlds +
                     ((rown * 128 + kc * 64 + lhi * 16) ^ ((rown & 7) << 4)));
        oacc[nt] = __builtin_amdgcn_mfma_f32_16x16x32_bf16(pa[kc], vb,
                                                           oacc[nt], 0, 0, 0);
      }
    }
  }

#pragma unroll
  for (int i = 0; i < 4; ++i) {
    const size_t row = (size_t)(b * LSEQ + qb * 64 + w * 16 + lhi * 4 + i);
    const float inv = 1.0f / lrow[i];
#pragma unroll
    for (int nt = 0; nt < 4; ++nt)
      o[row * 768 + hh * 64 + nt * 16 + l15] = f2bf(oacc[nt][i] * inv);
  }
}

// =====================================================================
extern "C" void kernel_launch(void* const* d_in, const int* in_sizes, int n_in,
                              void* d_out, int out_size, void* d_ws,
                              size_t ws_size, hipStream_t stream) {
  const float* x    = (const float*)d_in[0];
  const float* mask = (const float*)d_in[1];
  const float* pos  = (const float*)d_in[2];
  const float* caw  = (const float*)d_in[3];
  const float* cab  = (const float*)d_in[4];
  const float* apw  = (const float*)d_in[5];
  const float* apb  = (const float*)d_in[6];
  const float* g1   = (const float*)d_in[7];
  const float* b1   = (const float*)d_in[8];
  const float* fw   = (const float*)d_in[9];
  const float* fb   = (const float*)d_in[10];
  const float* pw   = (const float*)d_in[11];
  const float* pb   = (const float*)d_in[12];
  const float* g2   = (const float*)d_in[13];
  const float* b2   = (const float*)d_in[14];

  char* ws = (char*)d_ws;
  size_t off = 0;
  auto alloc = [&](size_t bytes) {
    size_t o = off;
    off += (bytes + 255) & ~(size_t)255;
    return o;
  };
  float* h    = (float*)(ws + alloc(8192ull * 768 * 4));
  short* hbf  = (short*)(ws + alloc(8192ull * 768 * 2));
  float* nrm  = (float*)(ws + alloc(8192ull * 768 * 4));
  short* nbf  = (short*)(ws + alloc(8192ull * 768 * 2));
  short* qkvb = (short*)(ws + alloc(8192ull * 2304 * 2));
  short* obf  = (short*)(ws + alloc(8192ull * 768 * 2));
  short* aout = (short*)(ws + alloc(8192ull * 768 * 2));  // proj/mlp bf16 out
  short* gbf  = (short*)(ws + alloc(8192ull * 3072 * 2));
  short* wt_attn = (short*)(ws + alloc(12ull * 768 * 2304 * 2));
  short* wt_proj = (short*)(ws + alloc(12ull * 768 * 768 * 2));
  short* wt_fc   = (short*)(ws + alloc(12ull * 768 * 3072 * 2));
  short* wt_mlp  = (short*)(ws + alloc(12ull * 3072 * 768 * 2));
  (void)ws_size; (void)in_sizes; (void)n_in; (void)out_size;

  wt_transpose<<<dim3(2304 / 32, 768 / 32, 12), 256, 0, stream>>>(caw, wt_attn, 768, 2304);
  wt_transpose<<<dim3(768 / 32, 768 / 32, 12), 256, 0, stream>>>(apw, wt_proj, 768, 768);
  wt_transpose<<<dim3(3072 / 32, 768 / 32, 12), 256, 0, stream>>>(fw, wt_fc, 768, 3072);
  wt_transpose<<<dim3(768 / 32, 3072 / 32, 12), 256, 0, stream>>>(pw, wt_mlp, 3072, 768);

  embed_k<<<8192, 256, 0, stream>>>(x, pos, h, hbf);

  for (int L = 0; L < 12; ++L) {
    gemm8<1><<<dim3(32, 9), 512, 0, stream>>>(
        hbf, wt_attn + (size_t)L * 2304 * 768, cab + (size_t)L * 2304, qkvb, 2304, 768);
    attn_k<<<dim3(8, 12, 16), 256, 0, stream>>>(qkvb, mask, obf);
    gemm_bt<64, 1><<<dim3(64, 12), 256, 0, stream>>>(
        obf, wt_proj + (size_t)L * 768 * 768, apb + (size_t)L * 768, aout, 768, 768);
    ln_fused<<<2048, 256, 0, stream>>>(h, aout, g1 + (size_t)L * 768,
                                       b1 + (size_t)L * 768, nrm, nbf);
    gemm8<2><<<dim3(32, 12), 512, 0, stream>>>(
        nbf, wt_fc + (size_t)L * 768 * 3072, fb + (size_t)L * 3072, gbf, 3072, 768);
    gemm_bt<64, 1><<<dim3(64, 12), 256, 0, stream>>>(
        gbf, wt_mlp + (size_t)L * 3072 * 768, pb + (size_t)L * 768, aout, 768, 3072);
    ln_fused<<<2048, 256, 0, stream>>>(nrm, aout, g2 + (size_t)L * 768,
                                       b2 + (size_t)L * 768, h, hbf);
  }

  final_k<<<8192, 256, 0, stream>>>(h, (float*)d_out);
}

// Round 7
// 3364.323 us; speedup vs baseline: 1.0552x; 1.0552x over previous
//
#include <hip/hip_runtime.h>
#include <cstdint>
#include <cstddef>

// GPT-12-layer forward, bf16 MFMA pipeline.
//   activations: rows = b*512 + l  (M = 8192), row-major, f32 residual + bf16 copy
//   weights: pre-transposed per layer to Wt[N][K] bf16
// qkv/fc GEMMs: 512-thr 128x256 tile, 2-phase (stage -> sync -> MFMA -> sync),
//   8 waves 2Mx4N (64x64/wave), BK=64, 48 KB LDS single-buffer,
//   XOR-swizzled (16B slot ^= row&7) via pre-swizzled global source.
// proj/mlp GEMMs (N=768): R2-proven 256-thr 128x64 tile, bf16 out.
// Attention: flash-style. LN: wave-per-row, vectorized, bf16 gemm-out + f32 residual.

#define LSEQ 512
#define NBATCH 16
#define EDIM 768
#define NHEAD 12
#define NLAYER 12

typedef __attribute__((ext_vector_type(8))) short short8;
typedef __attribute__((ext_vector_type(4))) short short4v;
typedef __attribute__((ext_vector_type(4))) float f32x4;

__device__ __forceinline__ short f2bf(float f) {
  union { float f; unsigned u; } x; x.f = f;
  return (short)((x.u + 0x7FFFu + ((x.u >> 16) & 1u)) >> 16);  // RNE
}
__device__ __forceinline__ float bf2f(short s) {
  union { unsigned u; float f; } x; x.u = ((unsigned)(unsigned short)s) << 16;
  return x.f;
}

__device__ __forceinline__ void gload_lds16(const void* g, void* l) {
  __builtin_amdgcn_global_load_lds(
      (__attribute__((address_space(1))) void*)(void*)g,
      (__attribute__((address_space(3))) void*)l, 16, 0, 0);
}

// ---------------- weight transpose + bf16 convert: W[K][N] f32 -> Wt[N][K] bf16
__global__ __launch_bounds__(256) void wt_transpose(const float* __restrict__ W,
                                                    short* __restrict__ Wt,
                                                    int K, int N) {
  __shared__ float tile[32][33];
  const int n0 = blockIdx.x * 32, k0 = blockIdx.y * 32;
  const size_t lo = (size_t)blockIdx.z * K * N;
  const float* Ws = W + lo;
  short* Wd = Wt + lo;
  const int tx = threadIdx.x & 31, ty = threadIdx.x >> 5;  // 32 x 8
#pragma unroll
  for (int i = 0; i < 4; ++i)
    tile[ty + i * 8][tx] = Ws[(size_t)(k0 + ty + i * 8) * N + n0 + tx];
  __syncthreads();
#pragma unroll
  for (int i = 0; i < 4; ++i)
    Wd[(size_t)(n0 + ty + i * 8) * K + k0 + tx] = f2bf(tile[tx][ty + i * 8]);
}

// ---------------- embed: h[b*L+l][e] = x[l][b][e] + pos[l][e]
__global__ __launch_bounds__(256) void embed_k(const float* __restrict__ x,
                                               const float* __restrict__ pos,
                                               float* __restrict__ h,
                                               short* __restrict__ hbf) {
  const int row = blockIdx.x;  // b*512 + l
  const int b = row >> 9, lp = row & 511;
  const int t = threadIdx.x;
#pragma unroll
  for (int i = 0; i < 3; ++i) {
    const int e = t + i * 256;
    float v = x[(size_t)(lp * 16 + b) * 768 + e] + pos[(size_t)lp * 768 + e];
    h[(size_t)row * 768 + e] = v;
    hbf[(size_t)row * 768 + e] = f2bf(v);
  }
}

// ---------------- final: out[l][b][e] = h[b*L+l][e]
__global__ __launch_bounds__(256) void final_k(const float* __restrict__ h,
                                               float* __restrict__ out) {
  const int row = blockIdx.x;  // l*16 + b
  const int lp = row >> 4, b = row & 15;
  const int t = threadIdx.x;
#pragma unroll
  for (int i = 0; i < 3; ++i) {
    const int e = t + i * 256;
    out[(size_t)row * 768 + e] = h[(size_t)(b * 512 + lp) * 768 + e];
  }
}

// ---------------- fused residual-add + LayerNorm, wave-per-row
// A: f32 residual, B: bf16 gemm-out; writes f32 residual + bf16 copy
__global__ __launch_bounds__(256) void ln_fused(const float* __restrict__ A,
                                                const short* __restrict__ B,
                                                const float* __restrict__ g,
                                                const float* __restrict__ be,
                                                float* __restrict__ outf,
                                                short* __restrict__ outb) {
  const int row = blockIdx.x * 4 + (threadIdx.x >> 6);
  const int l = threadIdx.x & 63;
  const size_t base = (size_t)row * 768;
  float v[12];
  float s1 = 0.f, s2 = 0.f;
#pragma unroll
  for (int j = 0; j < 3; ++j) {
    const int e = j * 256 + l * 4;
    f32x4 a = *(const f32x4*)&A[base + e];
    short4v b = *(const short4v*)&B[base + e];
#pragma unroll
    for (int q = 0; q < 4; ++q) {
      float x = a[q] + bf2f(b[q]);
      v[j * 4 + q] = x; s1 += x; s2 += x * x;
    }
  }
#pragma unroll
  for (int m = 1; m < 64; m <<= 1) {
    s1 += __shfl_xor(s1, m);
    s2 += __shfl_xor(s2, m);
  }
  const float mu = s1 * (1.f / 768.f);
  const float rs = rsqrtf(s2 * (1.f / 768.f) - mu * mu + 1e-5f);
#pragma unroll
  for (int j = 0; j < 3; ++j) {
    const int e = j * 256 + l * 4;
    f32x4 gv = *(const f32x4*)&g[e];
    f32x4 bv = *(const f32x4*)&be[e];
    f32x4 of; short4v ob;
#pragma unroll
    for (int q = 0; q < 4; ++q) {
      float o = (v[j * 4 + q] - mu) * rs * gv[q] + bv[q];
      of[q] = o; ob[q] = f2bf(o);
    }
    *(f32x4*)&outf[base + e] = of;
    *(short4v*)&outb[base + e] = ob;
  }
}

// ---------------- 512-thr 128x256 GEMM (qkv, fc): C = A * Bt^T + bias
// 8 waves 2Mx4N (64x64/wave), BK=64, 48 KB LDS, 2-phase.
// EPI: 1 = bf16 out, 2 = gelu(bf16) out
template <int EPI>
__global__ __launch_bounds__(512) void gemm512(const short* __restrict__ A,
                                               const short* __restrict__ Bt,
                                               const float* __restrict__ bias,
                                               short* __restrict__ C,
                                               int N, int K) {
  constexpr int BK = 64;  // shorts per row = 128B = 8 x 16B slots
  __shared__ alignas(16) short Alds[128 * BK];
  __shared__ alignas(16) short Blds[256 * BK];
  const int t = threadIdx.x;
  const int w = t >> 6, l = t & 63;
  const int wr = w >> 2, wc = w & 3;  // wave grid 2M x 4N, 64x64 per wave
  const int l15 = l & 15, lhi = l >> 4;
  const int rowA0 = blockIdx.x * 128;
  const int rowB0 = blockIdx.y * 256;

  f32x4 acc[4][4];
#pragma unroll
  for (int mi = 0; mi < 4; ++mi)
#pragma unroll
    for (int ni = 0; ni < 4; ++ni) acc[mi][ni] = (f32x4){0.f, 0.f, 0.f, 0.f};

  // staging: 512 threads cover a 64-row chunk (row = w*8 + (l>>3), slot = l&7)
  // LDS slot s holds global k-slot s^(r&7)  (pre-swizzled source)
  const int srl = w * 8 + (l >> 3);
  const int ss = l & 7;

  const short* aptr[2];
#pragma unroll
  for (int i = 0; i < 2; ++i) {
    const int r = i * 64 + srl;
    aptr[i] = A + (size_t)(rowA0 + r) * K + ((ss ^ (r & 7)) << 3);
  }
  const short* bptr[4];
#pragma unroll
  for (int i = 0; i < 4; ++i) {
    const int r = i * 64 + srl;
    bptr[i] = Bt + (size_t)(rowB0 + r) * K + ((ss ^ (r & 7)) << 3);
  }

  for (int kt = 0; kt < K; kt += BK) {
#pragma unroll
    for (int i = 0; i < 2; ++i) {
      gload_lds16(aptr[i], &Alds[(i * 64 + w * 8) * BK]);
      aptr[i] += BK;
    }
#pragma unroll
    for (int i = 0; i < 4; ++i) {
      gload_lds16(bptr[i], &Blds[(i * 64 + w * 8) * BK]);
      bptr[i] += BK;
    }
    __syncthreads();
    short8 af[4][2], bfr[4][2];
#pragma unroll
    for (int mi = 0; mi < 4; ++mi) {
      const int r = wr * 64 + mi * 16 + l15;
#pragma unroll
      for (int kc = 0; kc < 2; ++kc)
        af[mi][kc] = *(const short8*)
            &Alds[r * BK + ((((kc << 2) | lhi) ^ (r & 7)) << 3)];
    }
#pragma unroll
    for (int ni = 0; ni < 4; ++ni) {
      const int r = wc * 64 + ni * 16 + l15;
#pragma unroll
      for (int kc = 0; kc < 2; ++kc)
        bfr[ni][kc] = *(const short8*)
            &Blds[r * BK + ((((kc << 2) | lhi) ^ (r & 7)) << 3)];
    }
#pragma unroll
    for (int mi = 0; mi < 4; ++mi)
#pragma unroll
      for (int ni = 0; ni < 4; ++ni)
#pragma unroll
        for (int kc = 0; kc < 2; ++kc)
          acc[mi][ni] = __builtin_amdgcn_mfma_f32_16x16x32_bf16(
              af[mi][kc], bfr[ni][kc], acc[mi][ni], 0, 0, 0);
    __syncthreads();
  }

  float bv[4];
#pragma unroll
  for (int ni = 0; ni < 4; ++ni) bv[ni] = bias[rowB0 + wc * 64 + ni * 16 + l15];
#pragma unroll
  for (int mi = 0; mi < 4; ++mi) {
#pragma unroll
    for (int ni = 0; ni < 4; ++ni) {
      const int col = rowB0 + wc * 64 + ni * 16 + l15;
#pragma unroll
      for (int i = 0; i < 4; ++i) {
        const int row = rowA0 + wr * 64 + mi * 16 + lhi * 4 + i;
        float v = acc[mi][ni][i] + bv[ni];
        if constexpr (EPI == 1) {
          C[(size_t)row * N + col] = f2bf(v);
        } else {
          // gelu_new via sigmoid: 0.5x(1+tanh z) = x / (1 + exp(-2z))
          float pz = v * fmaf(0.044715f, v * v, 1.0f);
          float e = __expf(-1.5957691216057308f * pz);
          float r = __builtin_amdgcn_rcpf(1.0f + e);
          C[(size_t)row * N + col] = f2bf(v * r);
        }
      }
    }
  }
}

// ---------------- 2-phase GEMM for N=768 (proj, mlp): 128x64 tile, BK=64
// (R2-proven structure). EPI: 0 = f32 out, 1 = bf16 out
template <int TN, int EPI>
__global__ __launch_bounds__(256) void gemm_bt(const short* __restrict__ A,
                                               const short* __restrict__ Bt,
                                               const float* __restrict__ bias,
                                               void* __restrict__ C,
                                               int N, int K) {
  constexpr int BK = 64;
  __shared__ alignas(16) short Alds[128 * BK];
  __shared__ alignas(16) short Blds[TN * BK];
  const int t = threadIdx.x;
  const int w = t >> 6, l = t & 63;
  constexpr int WR = (TN == 128) ? 2 : 4;
  constexpr int WC = (TN == 128) ? 2 : 1;
  constexpr int WM = 128 / WR;
  constexpr int MI = WM / 16;
  constexpr int NI = (TN / WC) / 16;
  const int wr = (WC == 2) ? (w >> 1) : w;
  const int wc = (WC == 2) ? (w & 1) : 0;
  const int l15 = l & 15, lhi = l >> 4;
  const int rowA0 = blockIdx.x * 128;
  const int rowB0 = blockIdx.y * TN;
  f32x4 acc[MI][NI];
#pragma unroll
  for (int mi = 0; mi < MI; ++mi)
#pragma unroll
    for (int ni = 0; ni < NI; ++ni) acc[mi][ni] = (f32x4){0.f, 0.f, 0.f, 0.f};

  const int srl = l >> 3;
  const int ss = l & 7;

  for (int kt = 0; kt < K; kt += BK) {
#pragma unroll
    for (int i = 0; i < 4; ++i) {
      const int r = i * 32 + w * 8 + srl;
      gload_lds16(A + (size_t)(rowA0 + r) * K + kt + ((ss ^ (r & 7)) << 3),
                  &Alds[i * 2048 + w * 512]);
    }
#pragma unroll
    for (int i = 0; i < TN / 32; ++i) {
      const int r = i * 32 + w * 8 + srl;
      gload_lds16(Bt + (size_t)(rowB0 + r) * K + kt + ((ss ^ (r & 7)) << 3),
                  &Blds[i * 2048 + w * 512]);
    }
    __syncthreads();
    short8 af[MI][2], bfr[NI][2];
#pragma unroll
    for (int mi = 0; mi < MI; ++mi) {
      const int r = wr * WM + mi * 16 + l15;
#pragma unroll
      for (int kc = 0; kc < 2; ++kc)
        af[mi][kc] = *(const short8*)
            &Alds[r * 64 + ((((kc << 2) | lhi) ^ (r & 7)) << 3)];
    }
#pragma unroll
    for (int ni = 0; ni < NI; ++ni) {
      const int r = wc * 64 + ni * 16 + l15;
#pragma unroll
      for (int kc = 0; kc < 2; ++kc)
        bfr[ni][kc] = *(const short8*)
            &Blds[r * 64 + ((((kc << 2) | lhi) ^ (r & 7)) << 3)];
    }
#pragma unroll
    for (int mi = 0; mi < MI; ++mi)
#pragma unroll
      for (int ni = 0; ni < NI; ++ni)
#pragma unroll
        for (int kc = 0; kc < 2; ++kc)
          acc[mi][ni] = __builtin_amdgcn_mfma_f32_16x16x32_bf16(
              af[mi][kc], bfr[ni][kc], acc[mi][ni], 0, 0, 0);
    __syncthreads();
  }

  float bv[NI];
#pragma unroll
  for (int ni = 0; ni < NI; ++ni) bv[ni] = bias[rowB0 + wc * 64 + ni * 16 + l15];
#pragma unroll
  for (int mi = 0; mi < MI; ++mi) {
#pragma unroll
    for (int ni = 0; ni < NI; ++ni) {
      const int col = rowB0 + wc * 64 + ni * 16 + l15;
#pragma unroll
      for (int i = 0; i < 4; ++i) {
        const int row = rowA0 + wr * WM + mi * 16 + lhi * 4 + i;
        float v = acc[mi][ni][i] + bv[ni];
        if constexpr (EPI == 0) {
          ((float*)C)[(size_t)row * N + col] = v;
        } else {
          ((short*)C)[(size_t)row * N + col] = f2bf(v);
        }
      }
    }
  }
}

// ---------------- flash attention: block = (qb, head, batch), 4 waves
__global__ __launch_bounds__(256) void attn_k(const short* __restrict__ qkv,
                                              const float* __restrict__ mask,
                                              short* __restrict__ o) {
  const int qb = blockIdx.x;
  const int hh = blockIdx.y;
  const int b = blockIdx.z;
  const int t = threadIdx.x, w = t >> 6, l = t & 63;
  const int l15 = l & 15, lhi = l >> 4;
  __shared__ alignas(16) short Klds[64 * 64];
  __shared__ alignas(16) short Vlds[64 * 64];   // stored transposed: Vt[n][k]
  __shared__ alignas(16) short Plds[4][16 * 72];

  short8 qa[2];
  {
    const size_t base =
        (size_t)(b * LSEQ + qb * 64 + w * 16 + l15) * 2304 + hh * 64;
    qa[0] = *(const short8*)&qkv[base + lhi * 8];
    qa[1] = *(const short8*)&qkv[base + 32 + lhi * 8];
  }
  float mrow[4] = {-1e30f, -1e30f, -1e30f, -1e30f};
  float lrow[4] = {0.f, 0.f, 0.f, 0.f};
  const f32x4 zero4 = {0.f, 0.f, 0.f, 0.f};
  f32x4 oacc[4];
#pragma unroll
  for (int nt = 0; nt < 4; ++nt) oacc[nt] = zero4;

  const int nkt = qb + 1;
  for (int kt = 0; kt < nkt; ++kt) {
    __syncthreads();
    {
      const int kr = t >> 2, cc = (t & 3) * 16;
      const size_t grow = (size_t)(b * LSEQ + kt * 64 + kr) * 2304 + hh * 64;
      short8 k0 = *(const short8*)&qkv[grow + 768 + cc];
      short8 k1 = *(const short8*)&qkv[grow + 768 + cc + 8];
      short8 v0 = *(const short8*)&qkv[grow + 1536 + cc];
      short8 v1 = *(const short8*)&qkv[grow + 1536 + cc + 8];
      const int sw = (kr & 7) << 4;
      *(short8*)((char*)Klds + ((kr * 128 + cc * 2) ^ sw)) = k0;
      *(short8*)((char*)Klds + ((kr * 128 + cc * 2 + 16) ^ sw)) = k1;
#pragma unroll
      for (int e = 0; e < 8; ++e) {
        const int n0 = cc + e, n1 = cc + 8 + e;
        ((short*)Vlds)[((n0 * 128 + kr * 2) ^ ((n0 & 7) << 4)) >> 1] = v0[e];
        ((short*)Vlds)[((n1 * 128 + kr * 2) ^ ((n1 & 7) << 4)) >> 1] = v1[e];
      }
    }
    __syncthreads();

    f32x4 s[4];
#pragma unroll
    for (int jt = 0; jt < 4; ++jt) {
      f32x4 z = zero4;
#pragma unroll
      for (int kc = 0; kc < 2; ++kc) {
        const int rowk = jt * 16 + l15;
        short8 kb = *(const short8*)((char*)Klds +
                     ((rowk * 128 + kc * 64 + lhi * 16) ^ ((rowk & 7) << 4)));
        z = __builtin_amdgcn_mfma_f32_16x16x32_bf16(qa[kc], kb, z, 0, 0, 0);
      }
      s[jt] = z;
    }

    float addm[4];
#pragma unroll
    for (int jt = 0; jt < 4; ++jt)
      addm[jt] = (1.0f - mask[b * LSEQ + kt * 64 + jt * 16 + l15]) *
                 -3.402823466e38f;
#pragma unroll
    for (int jt = 0; jt < 4; ++jt) {
      const int colg = kt * 64 + jt * 16 + l15;
#pragma unroll
      for (int i = 0; i < 4; ++i) {
        const int rowg = qb * 64 + w * 16 + lhi * 4 + i;
        float sv = s[jt][i] * 0.125f;
        if (colg > rowg) sv = -10000.0f;
        s[jt][i] = sv + addm[jt];
      }
    }

    float mnew[4], sc[4];
#pragma unroll
    for (int i = 0; i < 4; ++i) {
      float tm = fmaxf(fmaxf(s[0][i], s[1][i]), fmaxf(s[2][i], s[3][i]));
#pragma unroll
      for (int mm = 1; mm < 16; mm <<= 1) tm = fmaxf(tm, __shfl_xor(tm, mm));
      mnew[i] = fmaxf(mrow[i], tm);
      sc[i] = __expf(mrow[i] - mnew[i]);
      mrow[i] = mnew[i];
    }
#pragma unroll
    for (int i = 0; i < 4; ++i) {
      float ts = 0.f;
#pragma unroll
      for (int jt = 0; jt < 4; ++jt) {
        float p = __expf(s[jt][i] - mnew[i]);
        s[jt][i] = p;
        ts += p;
      }
#pragma unroll
      for (int mm = 1; mm < 16; mm <<= 1) ts += __shfl_xor(ts, mm);
      lrow[i] = lrow[i] * sc[i] + ts;
      oacc[0][i] *= sc[i]; oacc[1][i] *= sc[i];
      oacc[2][i] *= sc[i]; oacc[3][i] *= sc[i];
    }

    short* Pw = &Plds[w][0];
#pragma unroll
    for (int jt = 0; jt < 4; ++jt)
#pragma unroll
      for (int i = 0; i < 4; ++i)
        Pw[(lhi * 4 + i) * 72 + jt * 16 + l15] = f2bf(s[jt][i]);
    __syncthreads();
    short8 pa[2];
#pragma unroll
    for (int kc = 0; kc < 2; ++kc)
      pa[kc] = *(const short8*)&Pw[l15 * 72 + kc * 32 + lhi * 8];

#pragma unroll
    for (int nt = 0; nt < 4; ++nt) {
#pragma unroll
      for (int kc = 0; kc < 2; ++kc) {
        const int rown = nt * 16 + l15;
        short8 vb = *(const short8*)((char*)Vlds +
                     ((rown * 128 + kc * 64 + lhi * 16) ^ ((rown & 7) << 4)));
        oacc[nt] = __builtin_amdgcn_mfma_f32_16x16x32_bf16(pa[kc], vb,
                                                           oacc[nt], 0, 0, 0);
      }
    }
  }

#pragma unroll
  for (int i = 0; i < 4; ++i) {
    const size_t row = (size_t)(b * LSEQ + qb * 64 + w * 16 + lhi * 4 + i);
    const float inv = 1.0f / lrow[i];
#pragma unroll
    for (int nt = 0; nt < 4; ++nt)
      o[row * 768 + hh * 64 + nt * 16 + l15] = f2bf(oacc[nt][i] * inv);
  }
}

// =====================================================================
extern "C" void kernel_launch(void* const* d_in, const int* in_sizes, int n_in,
                              void* d_out, int out_size, void* d_ws,
                              size_t ws_size, hipStream_t stream) {
  const float* x    = (const float*)d_in[0];
  const float* mask = (const float*)d_in[1];
  const float* pos  = (const float*)d_in[2];
  const float* caw  = (const float*)d_in[3];
  const float* cab  = (const float*)d_in[4];
  const float* apw  = (const float*)d_in[5];
  const float* apb  = (const float*)d_in[6];
  const float* g1   = (const float*)d_in[7];
  const float* b1   = (const float*)d_in[8];
  const float* fw   = (const float*)d_in[9];
  const float* fb   = (const float*)d_in[10];
  const float* pw   = (const float*)d_in[11];
  const float* pb   = (const float*)d_in[12];
  const float* g2   = (const float*)d_in[13];
  const float* b2   = (const float*)d_in[14];

  char* ws = (char*)d_ws;
  size_t off = 0;
  auto alloc = [&](size_t bytes) {
    size_t o = off;
    off += (bytes + 255) & ~(size_t)255;
    return o;
  };
  float* h    = (float*)(ws + alloc(8192ull * 768 * 4));
  short* hbf  = (short*)(ws + alloc(8192ull * 768 * 2));
  float* nrm  = (float*)(ws + alloc(8192ull * 768 * 4));
  short* nbf  = (short*)(ws + alloc(8192ull * 768 * 2));
  short* qkvb = (short*)(ws + alloc(8192ull * 2304 * 2));
  short* obf  = (short*)(ws + alloc(8192ull * 768 * 2));
  short* aout = (short*)(ws + alloc(8192ull * 768 * 2));  // proj/mlp bf16 out
  short* gbf  = (short*)(ws + alloc(8192ull * 3072 * 2));
  short* wt_attn = (short*)(ws + alloc(12ull * 768 * 2304 * 2));
  short* wt_proj = (short*)(ws + alloc(12ull * 768 * 768 * 2));
  short* wt_fc   = (short*)(ws + alloc(12ull * 768 * 3072 * 2));
  short* wt_mlp  = (short*)(ws + alloc(12ull * 3072 * 768 * 2));
  (void)ws_size; (void)in_sizes; (void)n_in; (void)out_size;

  wt_transpose<<<dim3(2304 / 32, 768 / 32, 12), 256, 0, stream>>>(caw, wt_attn, 768, 2304);
  wt_transpose<<<dim3(768 / 32, 768 / 32, 12), 256, 0, stream>>>(apw, wt_proj, 768, 768);
  wt_transpose<<<dim3(3072 / 32, 768 / 32, 12), 256, 0, stream>>>(fw, wt_fc, 768, 3072);
  wt_transpose<<<dim3(768 / 32, 3072 / 32, 12), 256, 0, stream>>>(pw, wt_mlp, 3072, 768);

  embed_k<<<8192, 256, 0, stream>>>(x, pos, h, hbf);

  for (int L = 0; L < 12; ++L) {
    gemm512<1><<<dim3(64, 9), 512, 0, stream>>>(
        hbf, wt_attn + (size_t)L * 2304 * 768, cab + (size_t)L * 2304, qkvb, 2304, 768);
    attn_k<<<dim3(8, 12, 16), 256, 0, stream>>>(qkvb, mask, obf);
    gemm_bt<64, 1><<<dim3(64, 12), 256, 0, stream>>>(
        obf, wt_proj + (size_t)L * 768 * 768, apb + (size_t)L * 768, aout, 768, 768);
    ln_fused<<<2048, 256, 0, stream>>>(h, aout, g1 + (size_t)L * 768,
                                       b1 + (size_t)L * 768, nrm, nbf);
    gemm512<2><<<dim3(64, 12), 512, 0, stream>>>(
        nbf, wt_fc + (size_t)L * 768 * 3072, fb + (size_t)L * 3072, gbf, 3072, 768);
    gemm_bt<64, 1><<<dim3(64, 12), 256, 0, stream>>>(
        gbf, wt_mlp + (size_t)L * 3072 * 768, pb + (size_t)L * 768, aout, 768, 3072);
    ln_fused<<<2048, 256, 0, stream>>>(nrm, aout, g2 + (size_t)L * 768,
                                       b2 + (size_t)L * 768, h, hbf);
  }

  final_k<<<8192, 256, 0, stream>>>(h, (float*)d_out);
}

// Round 8
// 3264.705 us; speedup vs baseline: 1.0874x; 1.0305x over previous
//
#include <hip/hip_runtime.h>
#include <cstdint>
#include <cstddef>

// GPT-12-layer forward, bf16 MFMA pipeline.
//   activations: rows = b*512 + l  (M = 8192), row-major, f32 residual + bf16 copy
//   weights: pre-transposed per layer to Wt[N][K] bf16
// qkv/fc GEMMs: 512-thr 128x256 tile, 2-phase, 8 waves 2Mx4N, BK=64.
// proj/mlp GEMMs (N=768): 256-thr 128x128 tile + split-K2 (blockIdx.z),
//   bf16 partials to two buffers, bias in z=0 only; LN does 3-input add.
// All GEMM LDS XOR-swizzled (16B slot ^= row&7) via pre-swizzled global source.
// Attention: flash-style. LN: wave-per-row, vectorized.

#define LSEQ 512
#define NBATCH 16
#define EDIM 768
#define NHEAD 12
#define NLAYER 12

typedef __attribute__((ext_vector_type(8))) short short8;
typedef __attribute__((ext_vector_type(4))) short short4v;
typedef __attribute__((ext_vector_type(4))) float f32x4;

__device__ __forceinline__ short f2bf(float f) {
  union { float f; unsigned u; } x; x.f = f;
  return (short)((x.u + 0x7FFFu + ((x.u >> 16) & 1u)) >> 16);  // RNE
}
__device__ __forceinline__ float bf2f(short s) {
  union { unsigned u; float f; } x; x.u = ((unsigned)(unsigned short)s) << 16;
  return x.f;
}

__device__ __forceinline__ void gload_lds16(const void* g, void* l) {
  __builtin_amdgcn_global_load_lds(
      (__attribute__((address_space(1))) void*)(void*)g,
      (__attribute__((address_space(3))) void*)l, 16, 0, 0);
}

// ---------------- weight transpose + bf16 convert: W[K][N] f32 -> Wt[N][K] bf16
__global__ __launch_bounds__(256) void wt_transpose(const float* __restrict__ W,
                                                    short* __restrict__ Wt,
                                                    int K, int N) {
  __shared__ float tile[32][33];
  const int n0 = blockIdx.x * 32, k0 = blockIdx.y * 32;
  const size_t lo = (size_t)blockIdx.z * K * N;
  const float* Ws = W + lo;
  short* Wd = Wt + lo;
  const int tx = threadIdx.x & 31, ty = threadIdx.x >> 5;  // 32 x 8
#pragma unroll
  for (int i = 0; i < 4; ++i)
    tile[ty + i * 8][tx] = Ws[(size_t)(k0 + ty + i * 8) * N + n0 + tx];
  __syncthreads();
#pragma unroll
  for (int i = 0; i < 4; ++i)
    Wd[(size_t)(n0 + ty + i * 8) * K + k0 + tx] = f2bf(tile[tx][ty + i * 8]);
}

// ---------------- embed: h[b*L+l][e] = x[l][b][e] + pos[l][e]
__global__ __launch_bounds__(256) void embed_k(const float* __restrict__ x,
                                               const float* __restrict__ pos,
                                               float* __restrict__ h,
                                               short* __restrict__ hbf) {
  const int row = blockIdx.x;  // b*512 + l
  const int b = row >> 9, lp = row & 511;
  const int t = threadIdx.x;
#pragma unroll
  for (int i = 0; i < 3; ++i) {
    const int e = t + i * 256;
    float v = x[(size_t)(lp * 16 + b) * 768 + e] + pos[(size_t)lp * 768 + e];
    h[(size_t)row * 768 + e] = v;
    hbf[(size_t)row * 768 + e] = f2bf(v);
  }
}

// ---------------- final: out[l][b][e] = h[b*L+l][e]
__global__ __launch_bounds__(256) void final_k(const float* __restrict__ h,
                                               float* __restrict__ out) {
  const int row = blockIdx.x;  // l*16 + b
  const int lp = row >> 4, b = row & 15;
  const int t = threadIdx.x;
#pragma unroll
  for (int i = 0; i < 3; ++i) {
    const int e = t + i * 256;
    out[(size_t)row * 768 + e] = h[(size_t)(b * 512 + lp) * 768 + e];
  }
}

// ---------------- fused residual-add + LayerNorm, wave-per-row
// x = A(f32) + B0(bf16 partial) + B1(bf16 partial); writes f32 + bf16
__global__ __launch_bounds__(256) void ln_fused(const float* __restrict__ A,
                                                const short* __restrict__ B0,
                                                const short* __restrict__ B1,
                                                const float* __restrict__ g,
                                                const float* __restrict__ be,
                                                float* __restrict__ outf,
                                                short* __restrict__ outb) {
  const int row = blockIdx.x * 4 + (threadIdx.x >> 6);
  const int l = threadIdx.x & 63;
  const size_t base = (size_t)row * 768;
  float v[12];
  float s1 = 0.f, s2 = 0.f;
#pragma unroll
  for (int j = 0; j < 3; ++j) {
    const int e = j * 256 + l * 4;
    f32x4 a = *(const f32x4*)&A[base + e];
    short4v b0 = *(const short4v*)&B0[base + e];
    short4v b1 = *(const short4v*)&B1[base + e];
#pragma unroll
    for (int q = 0; q < 4; ++q) {
      float x = a[q] + bf2f(b0[q]) + bf2f(b1[q]);
      v[j * 4 + q] = x; s1 += x; s2 += x * x;
    }
  }
#pragma unroll
  for (int m = 1; m < 64; m <<= 1) {
    s1 += __shfl_xor(s1, m);
    s2 += __shfl_xor(s2, m);
  }
  const float mu = s1 * (1.f / 768.f);
  const float rs = rsqrtf(s2 * (1.f / 768.f) - mu * mu + 1e-5f);
#pragma unroll
  for (int j = 0; j < 3; ++j) {
    const int e = j * 256 + l * 4;
    f32x4 gv = *(const f32x4*)&g[e];
    f32x4 bv = *(const f32x4*)&be[e];
    f32x4 of; short4v ob;
#pragma unroll
    for (int q = 0; q < 4; ++q) {
      float o = (v[j * 4 + q] - mu) * rs * gv[q] + bv[q];
      of[q] = o; ob[q] = f2bf(o);
    }
    *(f32x4*)&outf[base + e] = of;
    *(short4v*)&outb[base + e] = ob;
  }
}

// ---------------- 512-thr 128x256 GEMM (qkv, fc): C = A * Bt^T + bias
// 8 waves 2Mx4N (64x64/wave), BK=64, 48 KB LDS, 2-phase.
// EPI: 1 = bf16 out, 2 = gelu(bf16) out
template <int EPI>
__global__ __launch_bounds__(512) void gemm512(const short* __restrict__ A,
                                               const short* __restrict__ Bt,
                                               const float* __restrict__ bias,
                                               short* __restrict__ C,
                                               int N, int K) {
  constexpr int BK = 64;  // shorts per row = 128B = 8 x 16B slots
  __shared__ alignas(16) short Alds[128 * BK];
  __shared__ alignas(16) short Blds[256 * BK];
  const int t = threadIdx.x;
  const int w = t >> 6, l = t & 63;
  const int wr = w >> 2, wc = w & 3;  // wave grid 2M x 4N, 64x64 per wave
  const int l15 = l & 15, lhi = l >> 4;
  const int rowA0 = blockIdx.x * 128;
  const int rowB0 = blockIdx.y * 256;

  f32x4 acc[4][4];
#pragma unroll
  for (int mi = 0; mi < 4; ++mi)
#pragma unroll
    for (int ni = 0; ni < 4; ++ni) acc[mi][ni] = (f32x4){0.f, 0.f, 0.f, 0.f};

  // staging: 512 threads cover a 64-row chunk (row = w*8 + (l>>3), slot = l&7)
  const int srl = w * 8 + (l >> 3);
  const int ss = l & 7;

  const short* aptr[2];
#pragma unroll
  for (int i = 0; i < 2; ++i) {
    const int r = i * 64 + srl;
    aptr[i] = A + (size_t)(rowA0 + r) * K + ((ss ^ (r & 7)) << 3);
  }
  const short* bptr[4];
#pragma unroll
  for (int i = 0; i < 4; ++i) {
    const int r = i * 64 + srl;
    bptr[i] = Bt + (size_t)(rowB0 + r) * K + ((ss ^ (r & 7)) << 3);
  }

  for (int kt = 0; kt < K; kt += BK) {
#pragma unroll
    for (int i = 0; i < 2; ++i) {
      gload_lds16(aptr[i], &Alds[(i * 64 + w * 8) * BK]);
      aptr[i] += BK;
    }
#pragma unroll
    for (int i = 0; i < 4; ++i) {
      gload_lds16(bptr[i], &Blds[(i * 64 + w * 8) * BK]);
      bptr[i] += BK;
    }
    __syncthreads();
    short8 af[4][2], bfr[4][2];
#pragma unroll
    for (int mi = 0; mi < 4; ++mi) {
      const int r = wr * 64 + mi * 16 + l15;
#pragma unroll
      for (int kc = 0; kc < 2; ++kc)
        af[mi][kc] = *(const short8*)
            &Alds[r * BK + ((((kc << 2) | lhi) ^ (r & 7)) << 3)];
    }
#pragma unroll
    for (int ni = 0; ni < 4; ++ni) {
      const int r = wc * 64 + ni * 16 + l15;
#pragma unroll
      for (int kc = 0; kc < 2; ++kc)
        bfr[ni][kc] = *(const short8*)
            &Blds[r * BK + ((((kc << 2) | lhi) ^ (r & 7)) << 3)];
    }
#pragma unroll
    for (int mi = 0; mi < 4; ++mi)
#pragma unroll
      for (int ni = 0; ni < 4; ++ni)
#pragma unroll
        for (int kc = 0; kc < 2; ++kc)
          acc[mi][ni] = __builtin_amdgcn_mfma_f32_16x16x32_bf16(
              af[mi][kc], bfr[ni][kc], acc[mi][ni], 0, 0, 0);
    __syncthreads();
  }

  float bv[4];
#pragma unroll
  for (int ni = 0; ni < 4; ++ni) bv[ni] = bias[rowB0 + wc * 64 + ni * 16 + l15];
#pragma unroll
  for (int mi = 0; mi < 4; ++mi) {
#pragma unroll
    for (int ni = 0; ni < 4; ++ni) {
      const int col = rowB0 + wc * 64 + ni * 16 + l15;
#pragma unroll
      for (int i = 0; i < 4; ++i) {
        const int row = rowA0 + wr * 64 + mi * 16 + lhi * 4 + i;
        float v = acc[mi][ni][i] + bv[ni];
        if constexpr (EPI == 1) {
          C[(size_t)row * N + col] = f2bf(v);
        } else {
          // gelu_new via sigmoid: 0.5x(1+tanh z) = x / (1 + exp(-2z))
          float pz = v * fmaf(0.044715f, v * v, 1.0f);
          float e = __expf(-1.5957691216057308f * pz);
          float r = __builtin_amdgcn_rcpf(1.0f + e);
          C[(size_t)row * N + col] = f2bf(v * r);
        }
      }
    }
  }
}

// ---------------- split-K GEMM for N=768 (proj, mlp): 128x128 tile, BK=64,
// blockIdx.z = K-half. Partial z writes bf16 to C + z*M*N; bias only in z=0.
__global__ __launch_bounds__(256) void gemm_pk(const short* __restrict__ A,
                                               const short* __restrict__ Bt,
                                               const float* __restrict__ bias,
                                               short* __restrict__ C,
                                               int N, int Kfull) {
  constexpr int BK = 64;
  __shared__ alignas(16) short Alds[128 * BK];
  __shared__ alignas(16) short Blds[128 * BK];
  const int t = threadIdx.x;
  const int w = t >> 6, l = t & 63;
  const int wr = w >> 1, wc = w & 1;  // wave grid 2x2, 64x64 per wave
  const int l15 = l & 15, lhi = l >> 4;
  const int rowA0 = blockIdx.x * 128;
  const int rowB0 = blockIdx.y * 128;
  const int z = blockIdx.z;
  const int Ks = Kfull >> 1;          // this block's K range
  const int koff = z * Ks;
  short* Cp = C + (size_t)z * 8192 * N;

  f32x4 acc[4][4];
#pragma unroll
  for (int mi = 0; mi < 4; ++mi)
#pragma unroll
    for (int ni = 0; ni < 4; ++ni) acc[mi][ni] = (f32x4){0.f, 0.f, 0.f, 0.f};

  const int srl = l >> 3;   // 32-row chunks: row = i*32 + w*8 + srl
  const int ss = l & 7;

  const short* aptr[4];
  const short* bptr[4];
#pragma unroll
  for (int i = 0; i < 4; ++i) {
    const int r = i * 32 + w * 8 + srl;
    aptr[i] = A + (size_t)(rowA0 + r) * Kfull + koff + ((ss ^ (r & 7)) << 3);
    bptr[i] = Bt + (size_t)(rowB0 + r) * Kfull + koff + ((ss ^ (r & 7)) << 3);
  }

  for (int kt = 0; kt < Ks; kt += BK) {
#pragma unroll
    for (int i = 0; i < 4; ++i) {
      gload_lds16(aptr[i], &Alds[i * 2048 + w * 512]);
      gload_lds16(bptr[i], &Blds[i * 2048 + w * 512]);
      aptr[i] += BK; bptr[i] += BK;
    }
    __syncthreads();
    short8 af[4][2], bfr[4][2];
#pragma unroll
    for (int mi = 0; mi < 4; ++mi) {
      const int r = wr * 64 + mi * 16 + l15;
#pragma unroll
      for (int kc = 0; kc < 2; ++kc)
        af[mi][kc] = *(const short8*)
            &Alds[r * 64 + ((((kc << 2) | lhi) ^ (r & 7)) << 3)];
    }
#pragma unroll
    for (int ni = 0; ni < 4; ++ni) {
      const int r = wc * 64 + ni * 16 + l15;
#pragma unroll
      for (int kc = 0; kc < 2; ++kc)
        bfr[ni][kc] = *(const short8*)
            &Blds[r * 64 + ((((kc << 2) | lhi) ^ (r & 7)) << 3)];
    }
#pragma unroll
    for (int mi = 0; mi < 4; ++mi)
#pragma unroll
      for (int ni = 0; ni < 4; ++ni)
#pragma unroll
        for (int kc = 0; kc < 2; ++kc)
          acc[mi][ni] = __builtin_amdgcn_mfma_f32_16x16x32_bf16(
              af[mi][kc], bfr[ni][kc], acc[mi][ni], 0, 0, 0);
    __syncthreads();
  }

  float bv[4];
#pragma unroll
  for (int ni = 0; ni < 4; ++ni)
    bv[ni] = (z == 0) ? bias[rowB0 + wc * 64 + ni * 16 + l15] : 0.f;
#pragma unroll
  for (int mi = 0; mi < 4; ++mi) {
#pragma unroll
    for (int ni = 0; ni < 4; ++ni) {
      const int col = rowB0 + wc * 64 + ni * 16 + l15;
#pragma unroll
      for (int i = 0; i < 4; ++i) {
        const int row = rowA0 + wr * 64 + mi * 16 + lhi * 4 + i;
        Cp[(size_t)row * N + col] = f2bf(acc[mi][ni][i] + bv[ni]);
      }
    }
  }
}

// ---------------- flash attention: block = (qb, head, batch), 4 waves
__global__ __launch_bounds__(256) void attn_k(const short* __restrict__ qkv,
                                              const float* __restrict__ mask,
                                              short* __restrict__ o) {
  const int qb = blockIdx.x;
  const int hh = blockIdx.y;
  const int b = blockIdx.z;
  const int t = threadIdx.x, w = t >> 6, l = t & 63;
  const int l15 = l & 15, lhi = l >> 4;
  __shared__ alignas(16) short Klds[64 * 64];
  __shared__ alignas(16) short Vlds[64 * 64];   // stored transposed: Vt[n][k]
  __shared__ alignas(16) short Plds[4][16 * 72];

  short8 qa[2];
  {
    const size_t base =
        (size_t)(b * LSEQ + qb * 64 + w * 16 + l15) * 2304 + hh * 64;
    qa[0] = *(const short8*)&qkv[base + lhi * 8];
    qa[1] = *(const short8*)&qkv[base + 32 + lhi * 8];
  }
  float mrow[4] = {-1e30f, -1e30f, -1e30f, -1e30f};
  float lrow[4] = {0.f, 0.f, 0.f, 0.f};
  const f32x4 zero4 = {0.f, 0.f, 0.f, 0.f};
  f32x4 oacc[4];
#pragma unroll
  for (int nt = 0; nt < 4; ++nt) oacc[nt] = zero4;

  const int nkt = qb + 1;
  for (int kt = 0; kt < nkt; ++kt) {
    __syncthreads();
    {
      const int kr = t >> 2, cc = (t & 3) * 16;
      const size_t grow = (size_t)(b * LSEQ + kt * 64 + kr) * 2304 + hh * 64;
      short8 k0 = *(const short8*)&qkv[grow + 768 + cc];
      short8 k1 = *(const short8*)&qkv[grow + 768 + cc + 8];
      short8 v0 = *(const short8*)&qkv[grow + 1536 + cc];
      short8 v1 = *(const short8*)&qkv[grow + 1536 + cc + 8];
      const int sw = (kr & 7) << 4;
      *(short8*)((char*)Klds + ((kr * 128 + cc * 2) ^ sw)) = k0;
      *(short8*)((char*)Klds + ((kr * 128 + cc * 2 + 16) ^ sw)) = k1;
#pragma unroll
      for (int e = 0; e < 8; ++e) {
        const int n0 = cc + e, n1 = cc + 8 + e;
        ((short*)Vlds)[((n0 * 128 + kr * 2) ^ ((n0 & 7) << 4)) >> 1] = v0[e];
        ((short*)Vlds)[((n1 * 128 + kr * 2) ^ ((n1 & 7) << 4)) >> 1] = v1[e];
      }
    }
    __syncthreads();

    f32x4 s[4];
#pragma unroll
    for (int jt = 0; jt < 4; ++jt) {
      f32x4 z = zero4;
#pragma unroll
      for (int kc = 0; kc < 2; ++kc) {
        const int rowk = jt * 16 + l15;
        short8 kb = *(const short8*)((char*)Klds +
                     ((rowk * 128 + kc * 64 + lhi * 16) ^ ((rowk & 7) << 4)));
        z = __builtin_amdgcn_mfma_f32_16x16x32_bf16(qa[kc], kb, z, 0, 0, 0);
      }
      s[jt] = z;
    }

    float addm[4];
#pragma unroll
    for (int jt = 0; jt < 4; ++jt)
      addm[jt] = (1.0f - mask[b * LSEQ + kt * 64 + jt * 16 + l15]) *
                 -3.402823466e38f;
#pragma unroll
    for (int jt = 0; jt < 4; ++jt) {
      const int colg = kt * 64 + jt * 16 + l15;
#pragma unroll
      for (int i = 0; i < 4; ++i) {
        const int rowg = qb * 64 + w * 16 + lhi * 4 + i;
        float sv = s[jt][i] * 0.125f;
        if (colg > rowg) sv = -10000.0f;
        s[jt][i] = sv + addm[jt];
      }
    }

    float mnew[4], sc[4];
#pragma unroll
    for (int i = 0; i < 4; ++i) {
      float tm = fmaxf(fmaxf(s[0][i], s[1][i]), fmaxf(s[2][i], s[3][i]));
#pragma unroll
      for (int mm = 1; mm < 16; mm <<= 1) tm = fmaxf(tm, __shfl_xor(tm, mm));
      mnew[i] = fmaxf(mrow[i], tm);
      sc[i] = __expf(mrow[i] - mnew[i]);
      mrow[i] = mnew[i];
    }
#pragma unroll
    for (int i = 0; i < 4; ++i) {
      float ts = 0.f;
#pragma unroll
      for (int jt = 0; jt < 4; ++jt) {
        float p = __expf(s[jt][i] - mnew[i]);
        s[jt][i] = p;
        ts += p;
      }
#pragma unroll
      for (int mm = 1; mm < 16; mm <<= 1) ts += __shfl_xor(ts, mm);
      lrow[i] = lrow[i] * sc[i] + ts;
      oacc[0][i] *= sc[i]; oacc[1][i] *= sc[i];
      oacc[2][i] *= sc[i]; oacc[3][i] *= sc[i];
    }

    short* Pw = &Plds[w][0];
#pragma unroll
    for (int jt = 0; jt < 4; ++jt)
#pragma unroll
      for (int i = 0; i < 4; ++i)
        Pw[(lhi * 4 + i) * 72 + jt * 16 + l15] = f2bf(s[jt][i]);
    __syncthreads();
    short8 pa[2];
#pragma unroll
    for (int kc = 0; kc < 2; ++kc)
      pa[kc] = *(const short8*)&Pw[l15 * 72 + kc * 32 + lhi * 8];

#pragma unroll
    for (int nt = 0; nt < 4; ++nt) {
#pragma unroll
      for (int kc = 0; kc < 2; ++kc) {
        const int rown = nt * 16 + l15;
        short8 vb = *(const short8*)((char*)Vlds +
                     ((rown * 128 + kc * 64 + lhi * 16) ^ ((rown & 7) << 4)));
        oacc[nt] = __builtin_amdgcn_mfma_f32_16x16x32_bf16(pa[kc], vb,
                                                           oacc[nt], 0, 0, 0);
      }
    }
  }

#pragma unroll
  for (int i = 0; i < 4; ++i) {
    const size_t row = (size_t)(b * LSEQ + qb * 64 + w * 16 + lhi * 4 + i);
    const float inv = 1.0f / lrow[i];
#pragma unroll
    for (int nt = 0; nt < 4; ++nt)
      o[row * 768 + hh * 64 + nt * 16 + l15] = f2bf(oacc[nt][i] * inv);
  }
}

// =====================================================================
extern "C" void kernel_launch(void* const* d_in, const int* in_sizes, int n_in,
                              void* d_out, int out_size, void* d_ws,
                              size_t ws_size, hipStream_t stream) {
  const float* x    = (const float*)d_in[0];
  const float* mask = (const float*)d_in[1];
  const float* pos  = (const float*)d_in[2];
  const float* caw  = (const float*)d_in[3];
  const float* cab  = (const float*)d_in[4];
  const float* apw  = (const float*)d_in[5];
  const float* apb  = (const float*)d_in[6];
  const float* g1   = (const float*)d_in[7];
  const float* b1   = (const float*)d_in[8];
  const float* fw   = (const float*)d_in[9];
  const float* fb   = (const float*)d_in[10];
  const float* pw   = (const float*)d_in[11];
  const float* pb   = (const float*)d_in[12];
  const float* g2   = (const float*)d_in[13];
  const float* b2   = (const float*)d_in[14];

  char* ws = (char*)d_ws;
  size_t off = 0;
  auto alloc = [&](size_t bytes) {
    size_t o = off;
    off += (bytes + 255) & ~(size_t)255;
    return o;
  };
  float* h    = (float*)(ws + alloc(8192ull * 768 * 4));
  short* hbf  = (short*)(ws + alloc(8192ull * 768 * 2));
  float* nrm  = (float*)(ws + alloc(8192ull * 768 * 4));
  short* nbf  = (short*)(ws + alloc(8192ull * 768 * 2));
  short* qkvb = (short*)(ws + alloc(8192ull * 2304 * 2));
  short* obf  = (short*)(ws + alloc(8192ull * 768 * 2));
  short* aout = (short*)(ws + alloc(2ull * 8192 * 768 * 2));  // split-K partials
  short* gbf  = (short*)(ws + alloc(8192ull * 3072 * 2));
  short* wt_attn = (short*)(ws + alloc(12ull * 768 * 2304 * 2));
  short* wt_proj = (short*)(ws + alloc(12ull * 768 * 768 * 2));
  short* wt_fc   = (short*)(ws + alloc(12ull * 768 * 3072 * 2));
  short* wt_mlp  = (short*)(ws + alloc(12ull * 3072 * 768 * 2));
  short* aout1 = aout + 8192ull * 768;
  (void)ws_size; (void)in_sizes; (void)n_in; (void)out_size;

  wt_transpose<<<dim3(2304 / 32, 768 / 32, 12), 256, 0, stream>>>(caw, wt_attn, 768, 2304);
  wt_transpose<<<dim3(768 / 32, 768 / 32, 12), 256, 0, stream>>>(apw, wt_proj, 768, 768);
  wt_transpose<<<dim3(3072 / 32, 768 / 32, 12), 256, 0, stream>>>(fw, wt_fc, 768, 3072);
  wt_transpose<<<dim3(768 / 32, 3072 / 32, 12), 256, 0, stream>>>(pw, wt_mlp, 3072, 768);

  embed_k<<<8192, 256, 0, stream>>>(x, pos, h, hbf);

  for (int L = 0; L < 12; ++L) {
    gemm512<1><<<dim3(64, 9), 512, 0, stream>>>(
        hbf, wt_attn + (size_t)L * 2304 * 768, cab + (size_t)L * 2304, qkvb, 2304, 768);
    attn_k<<<dim3(8, 12, 16), 256, 0, stream>>>(qkvb, mask, obf);
    gemm_pk<<<dim3(64, 6, 2), 256, 0, stream>>>(
        obf, wt_proj + (size_t)L * 768 * 768, apb + (size_t)L * 768, aout, 768, 768);
    ln_fused<<<2048, 256, 0, stream>>>(h, aout, aout1, g1 + (size_t)L * 768,
                                       b1 + (size_t)L * 768, nrm, nbf);
    gemm512<2><<<dim3(64, 12), 512, 0, stream>>>(
        nbf, wt_fc + (size_t)L * 768 * 3072, fb + (size_t)L * 3072, gbf, 3072, 768);
    gemm_pk<<<dim3(64, 6, 2), 256, 0, stream>>>(
        gbf, wt_mlp + (size_t)L * 3072 * 768, pb + (size_t)L * 768, aout, 768, 3072);
    ln_fused<<<2048, 256, 0, stream>>>(nrm, aout, aout1, g2 + (size_t)L * 768,
                                       b2 + (size_t)L * 768, h, hbf);
  }

  final_k<<<8192, 256, 0, stream>>>(h, (float*)d_out);
}

// Round 9
// 3246.526 us; speedup vs baseline: 1.0935x; 1.0056x over previous
//
#include <hip/hip_runtime.h>
#include <cstdint>
#include <cstddef>

// GPT-12-layer forward, bf16 MFMA pipeline.
//   activations: rows = b*512 + l  (M = 8192), row-major, f32 residual + bf16 copy
//   weights: pre-transposed per layer to Wt[N][K] bf16
// qkv/fc GEMMs: 256-thr 64x256 tile, 4 waves 1Mx4N (64x64/wave), BK=64,
//   40 KB LDS, 2-phase; grid 1152/1536 blocks -> 4-6 blocks/CU (TLP lever).
// proj/mlp GEMMs (N=768): 128x128 tile + split-K2, bf16 partials; LN 3-input add.
// All GEMM LDS XOR-swizzled (16B slot ^= row&7) via pre-swizzled global source.
// Attention: flash-style. LN: wave-per-row, vectorized; layer-11 ln2 writes
//   d_out directly in (L,B,E) layout (final_k fused away).

#define LSEQ 512
#define NBATCH 16
#define EDIM 768
#define NHEAD 12
#define NLAYER 12

typedef __attribute__((ext_vector_type(8))) short short8;
typedef __attribute__((ext_vector_type(4))) short short4v;
typedef __attribute__((ext_vector_type(4))) float f32x4;

__device__ __forceinline__ short f2bf(float f) {
  union { float f; unsigned u; } x; x.f = f;
  return (short)((x.u + 0x7FFFu + ((x.u >> 16) & 1u)) >> 16);  // RNE
}
__device__ __forceinline__ float bf2f(short s) {
  union { unsigned u; float f; } x; x.u = ((unsigned)(unsigned short)s) << 16;
  return x.f;
}

__device__ __forceinline__ void gload_lds16(const void* g, void* l) {
  __builtin_amdgcn_global_load_lds(
      (__attribute__((address_space(1))) void*)(void*)g,
      (__attribute__((address_space(3))) void*)l, 16, 0, 0);
}

// ---------------- weight transpose + bf16 convert: W[K][N] f32 -> Wt[N][K] bf16
__global__ __launch_bounds__(256) void wt_transpose(const float* __restrict__ W,
                                                    short* __restrict__ Wt,
                                                    int K, int N) {
  __shared__ float tile[32][33];
  const int n0 = blockIdx.x * 32, k0 = blockIdx.y * 32;
  const size_t lo = (size_t)blockIdx.z * K * N;
  const float* Ws = W + lo;
  short* Wd = Wt + lo;
  const int tx = threadIdx.x & 31, ty = threadIdx.x >> 5;  // 32 x 8
#pragma unroll
  for (int i = 0; i < 4; ++i)
    tile[ty + i * 8][tx] = Ws[(size_t)(k0 + ty + i * 8) * N + n0 + tx];
  __syncthreads();
#pragma unroll
  for (int i = 0; i < 4; ++i)
    Wd[(size_t)(n0 + ty + i * 8) * K + k0 + tx] = f2bf(tile[tx][ty + i * 8]);
}

// ---------------- embed: h[b*L+l][e] = x[l][b][e] + pos[l][e]
__global__ __launch_bounds__(256) void embed_k(const float* __restrict__ x,
                                               const float* __restrict__ pos,
                                               float* __restrict__ h,
                                               short* __restrict__ hbf) {
  const int row = blockIdx.x;  // b*512 + l
  const int b = row >> 9, lp = row & 511;
  const int t = threadIdx.x;
#pragma unroll
  for (int i = 0; i < 3; ++i) {
    const int e = t + i * 256;
    float v = x[(size_t)(lp * 16 + b) * 768 + e] + pos[(size_t)lp * 768 + e];
    h[(size_t)row * 768 + e] = v;
    hbf[(size_t)row * 768 + e] = f2bf(v);
  }
}

// ---------------- fused residual-add + LayerNorm, wave-per-row
// x = A(f32) + B0(bf16 partial) + B1(bf16 partial); writes f32 + bf16.
// FINAL=1: writes ONLY f32 to out[(l*16+b)*768+e] (the harness output layout).
template <int FINAL>
__global__ __launch_bounds__(256) void ln_fused(const float* __restrict__ A,
                                                const short* __restrict__ B0,
                                                const short* __restrict__ B1,
                                                const float* __restrict__ g,
                                                const float* __restrict__ be,
                                                float* __restrict__ outf,
                                                short* __restrict__ outb) {
  const int row = blockIdx.x * 4 + (threadIdx.x >> 6);
  const int l = threadIdx.x & 63;
  const size_t base = (size_t)row * 768;
  float v[12];
  float s1 = 0.f, s2 = 0.f;
#pragma unroll
  for (int j = 0; j < 3; ++j) {
    const int e = j * 256 + l * 4;
    f32x4 a = *(const f32x4*)&A[base + e];
    short4v b0 = *(const short4v*)&B0[base + e];
    short4v b1 = *(const short4v*)&B1[base + e];
#pragma unroll
    for (int q = 0; q < 4; ++q) {
      float x = a[q] + bf2f(b0[q]) + bf2f(b1[q]);
      v[j * 4 + q] = x; s1 += x; s2 += x * x;
    }
  }
#pragma unroll
  for (int m = 1; m < 64; m <<= 1) {
    s1 += __shfl_xor(s1, m);
    s2 += __shfl_xor(s2, m);
  }
  const float mu = s1 * (1.f / 768.f);
  const float rs = rsqrtf(s2 * (1.f / 768.f) - mu * mu + 1e-5f);
  size_t obase = base;
  if constexpr (FINAL) {
    const int b = row >> 9, lp = row & 511;   // row = b*512+lp -> out lp*16+b
    obase = (size_t)(lp * 16 + b) * 768;
  }
#pragma unroll
  for (int j = 0; j < 3; ++j) {
    const int e = j * 256 + l * 4;
    f32x4 gv = *(const f32x4*)&g[e];
    f32x4 bv = *(const f32x4*)&be[e];
    f32x4 of; short4v ob;
#pragma unroll
    for (int q = 0; q < 4; ++q) {
      float o = (v[j * 4 + q] - mu) * rs * gv[q] + bv[q];
      of[q] = o; ob[q] = f2bf(o);
    }
    *(f32x4*)&outf[obase + e] = of;
    if constexpr (!FINAL) *(short4v*)&outb[obase + e] = ob;
  }
}

// ---------------- 256-thr 64x256 GEMM (qkv, fc): C = A * Bt^T + bias
// 4 waves 1Mx4N (64x64/wave), BK=64, 40 KB LDS, 2-phase.
// EPI: 1 = bf16 out, 2 = gelu(bf16) out
template <int EPI>
__global__ __launch_bounds__(256) void gemm256(const short* __restrict__ A,
                                               const short* __restrict__ Bt,
                                               const float* __restrict__ bias,
                                               short* __restrict__ C,
                                               int N, int K) {
  constexpr int BK = 64;  // shorts per row = 128B = 8 x 16B slots
  __shared__ alignas(16) short Alds[64 * BK];
  __shared__ alignas(16) short Blds[256 * BK];
  const int t = threadIdx.x;
  const int w = t >> 6, l = t & 63;
  const int wc = w;                  // wave = 64 rows x 64 cols (col block w)
  const int l15 = l & 15, lhi = l >> 4;
  const int rowA0 = blockIdx.x * 64;
  const int rowB0 = blockIdx.y * 256;

  f32x4 acc[4][4];
#pragma unroll
  for (int mi = 0; mi < 4; ++mi)
#pragma unroll
    for (int ni = 0; ni < 4; ++ni) acc[mi][ni] = (f32x4){0.f, 0.f, 0.f, 0.f};

  // staging: 32-row chunk per gload; row-in-chunk = w*8 + (l>>3), slot = l&7
  const int srl = w * 8 + (l >> 3);
  const int ss = l & 7;

  const short* aptr[2];
#pragma unroll
  for (int i = 0; i < 2; ++i) {
    const int r = i * 32 + srl;
    aptr[i] = A + (size_t)(rowA0 + r) * K + ((ss ^ (r & 7)) << 3);
  }
  const short* bptr[8];
#pragma unroll
  for (int i = 0; i < 8; ++i) {
    const int r = i * 32 + srl;
    bptr[i] = Bt + (size_t)(rowB0 + r) * K + ((ss ^ (r & 7)) << 3);
  }

  for (int kt = 0; kt < K; kt += BK) {
#pragma unroll
    for (int i = 0; i < 2; ++i) {
      gload_lds16(aptr[i], &Alds[(i * 32 + w * 8) * BK]);
      aptr[i] += BK;
    }
#pragma unroll
    for (int i = 0; i < 8; ++i) {
      gload_lds16(bptr[i], &Blds[(i * 32 + w * 8) * BK]);
      bptr[i] += BK;
    }
    __syncthreads();
    short8 af[4][2], bfr[4][2];
#pragma unroll
    for (int mi = 0; mi < 4; ++mi) {
      const int r = mi * 16 + l15;
#pragma unroll
      for (int kc = 0; kc < 2; ++kc)
        af[mi][kc] = *(const short8*)
            &Alds[r * BK + ((((kc << 2) | lhi) ^ (r & 7)) << 3)];
    }
#pragma unroll
    for (int ni = 0; ni < 4; ++ni) {
      const int r = wc * 64 + ni * 16 + l15;
#pragma unroll
      for (int kc = 0; kc < 2; ++kc)
        bfr[ni][kc] = *(const short8*)
            &Blds[r * BK + ((((kc << 2) | lhi) ^ (r & 7)) << 3)];
    }
#pragma unroll
    for (int mi = 0; mi < 4; ++mi)
#pragma unroll
      for (int ni = 0; ni < 4; ++ni)
#pragma unroll
        for (int kc = 0; kc < 2; ++kc)
          acc[mi][ni] = __builtin_amdgcn_mfma_f32_16x16x32_bf16(
              af[mi][kc], bfr[ni][kc], acc[mi][ni], 0, 0, 0);
    __syncthreads();
  }

  float bv[4];
#pragma unroll
  for (int ni = 0; ni < 4; ++ni) bv[ni] = bias[rowB0 + wc * 64 + ni * 16 + l15];
#pragma unroll
  for (int mi = 0; mi < 4; ++mi) {
#pragma unroll
    for (int ni = 0; ni < 4; ++ni) {
      const int col = rowB0 + wc * 64 + ni * 16 + l15;
#pragma unroll
      for (int i = 0; i < 4; ++i) {
        const int row = rowA0 + mi * 16 + lhi * 4 + i;
        float v = acc[mi][ni][i] + bv[ni];
        if constexpr (EPI == 1) {
          C[(size_t)row * N + col] = f2bf(v);
        } else {
          // gelu_new via sigmoid: 0.5x(1+tanh z) = x / (1 + exp(-2z))
          float pz = v * fmaf(0.044715f, v * v, 1.0f);
          float e = __expf(-1.5957691216057308f * pz);
          float r = __builtin_amdgcn_rcpf(1.0f + e);
          C[(size_t)row * N + col] = f2bf(v * r);
        }
      }
    }
  }
}

// ---------------- split-K GEMM for N=768 (proj, mlp): 128x128 tile, BK=64,
// blockIdx.z = K-half. Partial z writes bf16 to C + z*M*N; bias only in z=0.
__global__ __launch_bounds__(256) void gemm_pk(const short* __restrict__ A,
                                               const short* __restrict__ Bt,
                                               const float* __restrict__ bias,
                                               short* __restrict__ C,
                                               int N, int Kfull) {
  constexpr int BK = 64;
  __shared__ alignas(16) short Alds[128 * BK];
  __shared__ alignas(16) short Blds[128 * BK];
  const int t = threadIdx.x;
  const int w = t >> 6, l = t & 63;
  const int wr = w >> 1, wc = w & 1;  // wave grid 2x2, 64x64 per wave
  const int l15 = l & 15, lhi = l >> 4;
  const int rowA0 = blockIdx.x * 128;
  const int rowB0 = blockIdx.y * 128;
  const int z = blockIdx.z;
  const int Ks = Kfull >> 1;
  const int koff = z * Ks;
  short* Cp = C + (size_t)z * 8192 * N;

  f32x4 acc[4][4];
#pragma unroll
  for (int mi = 0; mi < 4; ++mi)
#pragma unroll
    for (int ni = 0; ni < 4; ++ni) acc[mi][ni] = (f32x4){0.f, 0.f, 0.f, 0.f};

  const int srl = l >> 3;
  const int ss = l & 7;

  const short* aptr[4];
  const short* bptr[4];
#pragma unroll
  for (int i = 0; i < 4; ++i) {
    const int r = i * 32 + w * 8 + srl;
    aptr[i] = A + (size_t)(rowA0 + r) * Kfull + koff + ((ss ^ (r & 7)) << 3);
    bptr[i] = Bt + (size_t)(rowB0 + r) * Kfull + koff + ((ss ^ (r & 7)) << 3);
  }

  for (int kt = 0; kt < Ks; kt += BK) {
#pragma unroll
    for (int i = 0; i < 4; ++i) {
      gload_lds16(aptr[i], &Alds[i * 2048 + w * 512]);
      gload_lds16(bptr[i], &Blds[i * 2048 + w * 512]);
      aptr[i] += BK; bptr[i] += BK;
    }
    __syncthreads();
    short8 af[4][2], bfr[4][2];
#pragma unroll
    for (int mi = 0; mi < 4; ++mi) {
      const int r = wr * 64 + mi * 16 + l15;
#pragma unroll
      for (int kc = 0; kc < 2; ++kc)
        af[mi][kc] = *(const short8*)
            &Alds[r * 64 + ((((kc << 2) | lhi) ^ (r & 7)) << 3)];
    }
#pragma unroll
    for (int ni = 0; ni < 4; ++ni) {
      const int r = wc * 64 + ni * 16 + l15;
#pragma unroll
      for (int kc = 0; kc < 2; ++kc)
        bfr[ni][kc] = *(const short8*)
            &Blds[r * 64 + ((((kc << 2) | lhi) ^ (r & 7)) << 3)];
    }
#pragma unroll
    for (int mi = 0; mi < 4; ++mi)
#pragma unroll
      for (int ni = 0; ni < 4; ++ni)
#pragma unroll
        for (int kc = 0; kc < 2; ++kc)
          acc[mi][ni] = __builtin_amdgcn_mfma_f32_16x16x32_bf16(
              af[mi][kc], bfr[ni][kc], acc[mi][ni], 0, 0, 0);
    __syncthreads();
  }

  float bv[4];
#pragma unroll
  for (int ni = 0; ni < 4; ++ni)
    bv[ni] = (z == 0) ? bias[rowB0 + wc * 64 + ni * 16 + l15] : 0.f;
#pragma unroll
  for (int mi = 0; mi < 4; ++mi) {
#pragma unroll
    for (int ni = 0; ni < 4; ++ni) {
      const int col = rowB0 + wc * 64 + ni * 16 + l15;
#pragma unroll
      for (int i = 0; i < 4; ++i) {
        const int row = rowA0 + wr * 64 + mi * 16 + lhi * 4 + i;
        Cp[(size_t)row * N + col] = f2bf(acc[mi][ni][i] + bv[ni]);
      }
    }
  }
}

// ---------------- flash attention: block = (qb, head, batch), 4 waves
__global__ __launch_bounds__(256) void attn_k(const short* __restrict__ qkv,
                                              const float* __restrict__ mask,
                                              short* __restrict__ o) {
  const int qb = blockIdx.x;
  const int hh = blockIdx.y;
  const int b = blockIdx.z;
  const int t = threadIdx.x, w = t >> 6, l = t & 63;
  const int l15 = l & 15, lhi = l >> 4;
  __shared__ alignas(16) short Klds[64 * 64];
  __shared__ alignas(16) short Vlds[64 * 64];   // stored transposed: Vt[n][k]
  __shared__ alignas(16) short Plds[4][16 * 72];

  short8 qa[2];
  {
    const size_t base =
        (size_t)(b * LSEQ + qb * 64 + w * 16 + l15) * 2304 + hh * 64;
    qa[0] = *(const short8*)&qkv[base + lhi * 8];
    qa[1] = *(const short8*)&qkv[base + 32 + lhi * 8];
  }
  float mrow[4] = {-1e30f, -1e30f, -1e30f, -1e30f};
  float lrow[4] = {0.f, 0.f, 0.f, 0.f};
  const f32x4 zero4 = {0.f, 0.f, 0.f, 0.f};
  f32x4 oacc[4];
#pragma unroll
  for (int nt = 0; nt < 4; ++nt) oacc[nt] = zero4;

  const int nkt = qb + 1;
  for (int kt = 0; kt < nkt; ++kt) {
    __syncthreads();
    {
      const int kr = t >> 2, cc = (t & 3) * 16;
      const size_t grow = (size_t)(b * LSEQ + kt * 64 + kr) * 2304 + hh * 64;
      short8 k0 = *(const short8*)&qkv[grow + 768 + cc];
      short8 k1 = *(const short8*)&qkv[grow + 768 + cc + 8];
      short8 v0 = *(const short8*)&qkv[grow + 1536 + cc];
      short8 v1 = *(const short8*)&qkv[grow + 1536 + cc + 8];
      const int sw = (kr & 7) << 4;
      *(short8*)((char*)Klds + ((kr * 128 + cc * 2) ^ sw)) = k0;
      *(short8*)((char*)Klds + ((kr * 128 + cc * 2 + 16) ^ sw)) = k1;
#pragma unroll
      for (int e = 0; e < 8; ++e) {
        const int n0 = cc + e, n1 = cc + 8 + e;
        ((short*)Vlds)[((n0 * 128 + kr * 2) ^ ((n0 & 7) << 4)) >> 1] = v0[e];
        ((short*)Vlds)[((n1 * 128 + kr * 2) ^ ((n1 & 7) << 4)) >> 1] = v1[e];
      }
    }
    __syncthreads();

    f32x4 s[4];
#pragma unroll
    for (int jt = 0; jt < 4; ++jt) {
      f32x4 z = zero4;
#pragma unroll
      for (int kc = 0; kc < 2; ++kc) {
        const int rowk = jt * 16 + l15;
        short8 kb = *(const short8*)((char*)Klds +
                     ((rowk * 128 + kc * 64 + lhi * 16) ^ ((rowk & 7) << 4)));
        z = __builtin_amdgcn_mfma_f32_16x16x32_bf16(qa[kc], kb, z, 0, 0, 0);
      }
      s[jt] = z;
    }

    float addm[4];
#pragma unroll
    for (int jt = 0; jt < 4; ++jt)
      addm[jt] = (1.0f - mask[b * LSEQ + kt * 64 + jt * 16 + l15]) *
                 -3.402823466e38f;
#pragma unroll
    for (int jt = 0; jt < 4; ++jt) {
      const int colg = kt * 64 + jt * 16 + l15;
#pragma unroll
      for (int i = 0; i < 4; ++i) {
        const int rowg = qb * 64 + w * 16 + lhi * 4 + i;
        float sv = s[jt][i] * 0.125f;
        if (colg > rowg) sv = -10000.0f;
        s[jt][i] = sv + addm[jt];
      }
    }

    float mnew[4], sc[4];
#pragma unroll
    for (int i = 0; i < 4; ++i) {
      float tm = fmaxf(fmaxf(s[0][i], s[1][i]), fmaxf(s[2][i], s[3][i]));
#pragma unroll
      for (int mm = 1; mm < 16; mm <<= 1) tm = fmaxf(tm, __shfl_xor(tm, mm));
      mnew[i] = fmaxf(mrow[i], tm);
      sc[i] = __expf(mrow[i] - mnew[i]);
      mrow[i] = mnew[i];
    }
#pragma unroll
    for (int i = 0; i < 4; ++i) {
      float ts = 0.f;
#pragma unroll
      for (int jt = 0; jt < 4; ++jt) {
        float p = __expf(s[jt][i] - mnew[i]);
        s[jt][i] = p;
        ts += p;
      }
#pragma unroll
      for (int mm = 1; mm < 16; mm <<= 1) ts += __shfl_xor(ts, mm);
      lrow[i] = lrow[i] * sc[i] + ts;
      oacc[0][i] *= sc[i]; oacc[1][i] *= sc[i];
      oacc[2][i] *= sc[i]; oacc[3][i] *= sc[i];
    }

    short* Pw = &Plds[w][0];
#pragma unroll
    for (int jt = 0; jt < 4; ++jt)
#pragma unroll
      for (int i = 0; i < 4; ++i)
        Pw[(lhi * 4 + i) * 72 + jt * 16 + l15] = f2bf(s[jt][i]);
    __syncthreads();
    short8 pa[2];
#pragma unroll
    for (int kc = 0; kc < 2; ++kc)
      pa[kc] = *(const short8*)&Pw[l15 * 72 + kc * 32 + lhi * 8];

#pragma unroll
    for (int nt = 0; nt < 4; ++nt) {
#pragma unroll
      for (int kc = 0; kc < 2; ++kc) {
        const int rown = nt * 16 + l15;
        short8 vb = *(const short8*)((char*)Vlds +
                     ((rown * 128 + kc * 64 + lhi * 16) ^ ((rown & 7) << 4)));
        oacc[nt] = __builtin_amdgcn_mfma_f32_16x16x32_bf16(pa[kc], vb,
                                                           oacc[nt], 0, 0, 0);
      }
    }
  }

#pragma unroll
  for (int i = 0; i < 4; ++i) {
    const size_t row = (size_t)(b * LSEQ + qb * 64 + w * 16 + lhi * 4 + i);
    const float inv = 1.0f / lrow[i];
#pragma unroll
    for (int nt = 0; nt < 4; ++nt)
      o[row * 768 + hh * 64 + nt * 16 + l15] = f2bf(oacc[nt][i] * inv);
  }
}

// =====================================================================
extern "C" void kernel_launch(void* const* d_in, const int* in_sizes, int n_in,
                              void* d_out, int out_size, void* d_ws,
                              size_t ws_size, hipStream_t stream) {
  const float* x    = (const float*)d_in[0];
  const float* mask = (const float*)d_in[1];
  const float* pos  = (const float*)d_in[2];
  const float* caw  = (const float*)d_in[3];
  const float* cab  = (const float*)d_in[4];
  const float* apw  = (const float*)d_in[5];
  const float* apb  = (const float*)d_in[6];
  const float* g1   = (const float*)d_in[7];
  const float* b1   = (const float*)d_in[8];
  const float* fw   = (const float*)d_in[9];
  const float* fb   = (const float*)d_in[10];
  const float* pw   = (const float*)d_in[11];
  const float* pb   = (const float*)d_in[12];
  const float* g2   = (const float*)d_in[13];
  const float* b2   = (const float*)d_in[14];

  char* ws = (char*)d_ws;
  size_t off = 0;
  auto alloc = [&](size_t bytes) {
    size_t o = off;
    off += (bytes + 255) & ~(size_t)255;
    return o;
  };
  float* h    = (float*)(ws + alloc(8192ull * 768 * 4));
  short* hbf  = (short*)(ws + alloc(8192ull * 768 * 2));
  float* nrm  = (float*)(ws + alloc(8192ull * 768 * 4));
  short* nbf  = (short*)(ws + alloc(8192ull * 768 * 2));
  short* qkvb = (short*)(ws + alloc(8192ull * 2304 * 2));
  short* obf  = (short*)(ws + alloc(8192ull * 768 * 2));
  short* aout = (short*)(ws + alloc(2ull * 8192 * 768 * 2));  // split-K partials
  short* gbf  = (short*)(ws + alloc(8192ull * 3072 * 2));
  short* wt_attn = (short*)(ws + alloc(12ull * 768 * 2304 * 2));
  short* wt_proj = (short*)(ws + alloc(12ull * 768 * 768 * 2));
  short* wt_fc   = (short*)(ws + alloc(12ull * 768 * 3072 * 2));
  short* wt_mlp  = (short*)(ws + alloc(12ull * 3072 * 768 * 2));
  short* aout1 = aout + 8192ull * 768;
  (void)ws_size; (void)in_sizes; (void)n_in; (void)out_size;

  wt_transpose<<<dim3(2304 / 32, 768 / 32, 12), 256, 0, stream>>>(caw, wt_attn, 768, 2304);
  wt_transpose<<<dim3(768 / 32, 768 / 32, 12), 256, 0, stream>>>(apw, wt_proj, 768, 768);
  wt_transpose<<<dim3(3072 / 32, 768 / 32, 12), 256, 0, stream>>>(fw, wt_fc, 768, 3072);
  wt_transpose<<<dim3(768 / 32, 3072 / 32, 12), 256, 0, stream>>>(pw, wt_mlp, 3072, 768);

  embed_k<<<8192, 256, 0, stream>>>(x, pos, h, hbf);

  for (int L = 0; L < 12; ++L) {
    gemm256<1><<<dim3(128, 9), 256, 0, stream>>>(
        hbf, wt_attn + (size_t)L * 2304 * 768, cab + (size_t)L * 2304, qkvb, 2304, 768);
    attn_k<<<dim3(8, 12, 16), 256, 0, stream>>>(qkvb, mask, obf);
    gemm_pk<<<dim3(64, 6, 2), 256, 0, stream>>>(
        obf, wt_proj + (size_t)L * 768 * 768, apb + (size_t)L * 768, aout, 768, 768);
    ln_fused<0><<<2048, 256, 0, stream>>>(h, aout, aout1, g1 + (size_t)L * 768,
                                          b1 + (size_t)L * 768, nrm, nbf);
    gemm256<2><<<dim3(128, 12), 256, 0, stream>>>(
        nbf, wt_fc + (size_t)L * 768 * 3072, fb + (size_t)L * 3072, gbf, 3072, 768);
    gemm_pk<<<dim3(64, 6, 2), 256, 0, stream>>>(
        gbf, wt_mlp + (size_t)L * 3072 * 768, pb + (size_t)L * 768, aout, 768, 3072);
    if (L < 11) {
      ln_fused<0><<<2048, 256, 0, stream>>>(nrm, aout, aout1, g2 + (size_t)L * 768,
                                            b2 + (size_t)L * 768, h, hbf);
    } else {
      ln_fused<1><<<2048, 256, 0, stream>>>(nrm, aout, aout1, g2 + (size_t)L * 768,
                                            b2 + (size_t)L * 768, (float*)d_out,
                                            nullptr);
    }
  }
}

// Round 10
// 3195.329 us; speedup vs baseline: 1.1110x; 1.0160x over previous
//
#include <hip/hip_runtime.h>
#include <cstdint>
#include <cstddef>

// GPT-12-layer forward, bf16 MFMA pipeline.
//   residual stream: bf16 (LN outputs), rows = b*512+l (M=8192), row-major
//   weights pre-transposed per layer to Wt[N][K] bf16
// qkv GEMM (gemm256): 64x256 tile; epilogue writes Q,K to qkvb and V
//   PRE-TRANSPOSED to vT[768][8192] (V-tiles are block-uniform: 1536%256==0).
// fc GEMM (gemm512): 128x256 tile, 512 thr, gelu epilogue (R8-proven, 65us).
// proj/mlp: 128x128 + split-K2, bf16 partials; LN does 3-input add.
// attn: flash-style; K and V^T staged via global_load_lds (linear dest +
//   pre-swizzled source), no in-kernel transpose, no reg staging.
// All GEMM LDS XOR-swizzled (16B slot ^= row&7) via pre-swizzled global source.

#define LSEQ 512
#define NBATCH 16
#define EDIM 768
#define NHEAD 12
#define NLAYER 12

typedef __attribute__((ext_vector_type(8))) short short8;
typedef __attribute__((ext_vector_type(4))) short short4v;
typedef __attribute__((ext_vector_type(4))) float f32x4;

__device__ __forceinline__ short f2bf(float f) {
  union { float f; unsigned u; } x; x.f = f;
  return (short)((x.u + 0x7FFFu + ((x.u >> 16) & 1u)) >> 16);  // RNE
}
__device__ __forceinline__ float bf2f(short s) {
  union { unsigned u; float f; } x; x.u = ((unsigned)(unsigned short)s) << 16;
  return x.f;
}

__device__ __forceinline__ void gload_lds16(const void* g, void* l) {
  __builtin_amdgcn_global_load_lds(
      (__attribute__((address_space(1))) void*)(void*)g,
      (__attribute__((address_space(3))) void*)l, 16, 0, 0);
}

// ---------------- weight transpose + bf16 convert: W[K][N] f32 -> Wt[N][K] bf16
__global__ __launch_bounds__(256) void wt_transpose(const float* __restrict__ W,
                                                    short* __restrict__ Wt,
                                                    int K, int N) {
  __shared__ float tile[32][33];
  const int n0 = blockIdx.x * 32, k0 = blockIdx.y * 32;
  const size_t lo = (size_t)blockIdx.z * K * N;
  const float* Ws = W + lo;
  short* Wd = Wt + lo;
  const int tx = threadIdx.x & 31, ty = threadIdx.x >> 5;  // 32 x 8
#pragma unroll
  for (int i = 0; i < 4; ++i)
    tile[ty + i * 8][tx] = Ws[(size_t)(k0 + ty + i * 8) * N + n0 + tx];
  __syncthreads();
#pragma unroll
  for (int i = 0; i < 4; ++i)
    Wd[(size_t)(n0 + ty + i * 8) * K + k0 + tx] = f2bf(tile[tx][ty + i * 8]);
}

// ---------------- embed: hbf[b*L+l][e] = bf16(x[l][b][e] + pos[l][e])
__global__ __launch_bounds__(256) void embed_k(const float* __restrict__ x,
                                               const float* __restrict__ pos,
                                               short* __restrict__ hbf) {
  const int row = blockIdx.x;  // b*512 + l
  const int b = row >> 9, lp = row & 511;
  const int t = threadIdx.x;
#pragma unroll
  for (int i = 0; i < 3; ++i) {
    const int e = t + i * 256;
    float v = x[(size_t)(lp * 16 + b) * 768 + e] + pos[(size_t)lp * 768 + e];
    hbf[(size_t)row * 768 + e] = f2bf(v);
  }
}

// ---------------- fused residual-add + LayerNorm, wave-per-row
// x = A(bf16 residual) + B0 + B1 (bf16 split-K partials); f32 math.
// FINAL=0: writes bf16 (serves as next GEMM input AND next residual).
// FINAL=1: writes f32 to out[(l*16+b)*768+e] (harness output layout).
template <int FINAL>
__global__ __launch_bounds__(256) void ln_fused(const short* __restrict__ A,
                                                const short* __restrict__ B0,
                                                const short* __restrict__ B1,
                                                const float* __restrict__ g,
                                                const float* __restrict__ be,
                                                void* __restrict__ out) {
  const int row = blockIdx.x * 4 + (threadIdx.x >> 6);
  const int l = threadIdx.x & 63;
  const size_t base = (size_t)row * 768;
  float v[12];
  float s1 = 0.f, s2 = 0.f;
#pragma unroll
  for (int j = 0; j < 3; ++j) {
    const int e = j * 256 + l * 4;
    short4v a = *(const short4v*)&A[base + e];
    short4v b0 = *(const short4v*)&B0[base + e];
    short4v b1 = *(const short4v*)&B1[base + e];
#pragma unroll
    for (int q = 0; q < 4; ++q) {
      float x = bf2f(a[q]) + bf2f(b0[q]) + bf2f(b1[q]);
      v[j * 4 + q] = x; s1 += x; s2 += x * x;
    }
  }
#pragma unroll
  for (int m = 1; m < 64; m <<= 1) {
    s1 += __shfl_xor(s1, m);
    s2 += __shfl_xor(s2, m);
  }
  const float mu = s1 * (1.f / 768.f);
  const float rs = rsqrtf(s2 * (1.f / 768.f) - mu * mu + 1e-5f);
  size_t obase = base;
  if constexpr (FINAL) {
    const int b = row >> 9, lp = row & 511;   // row = b*512+lp -> out lp*16+b
    obase = (size_t)(lp * 16 + b) * 768;
  }
#pragma unroll
  for (int j = 0; j < 3; ++j) {
    const int e = j * 256 + l * 4;
    f32x4 gv = *(const f32x4*)&g[e];
    f32x4 bv = *(const f32x4*)&be[e];
    if constexpr (FINAL) {
      f32x4 of;
#pragma unroll
      for (int q = 0; q < 4; ++q)
        of[q] = (v[j * 4 + q] - mu) * rs * gv[q] + bv[q];
      *(f32x4*)&((float*)out)[obase + e] = of;
    } else {
      short4v ob;
#pragma unroll
      for (int q = 0; q < 4; ++q)
        ob[q] = f2bf((v[j * 4 + q] - mu) * rs * gv[q] + bv[q]);
      *(short4v*)&((short*)out)[obase + e] = ob;
    }
  }
}

// ---------------- qkv GEMM: 256-thr 64x256 tile, 4 waves 1Mx4N, BK=64.
// Q,K columns -> qkvb[row][col]; V columns -> Vt[(col-1536)][row] (transposed).
__global__ __launch_bounds__(256) void gemm_qkv(const short* __restrict__ A,
                                                const short* __restrict__ Bt,
                                                const float* __restrict__ bias,
                                                short* __restrict__ C,
                                                short* __restrict__ Vt,
                                                int N, int K) {
  constexpr int BK = 64;
  __shared__ alignas(16) short Alds[64 * BK];
  __shared__ alignas(16) short Blds[256 * BK];
  const int t = threadIdx.x;
  const int w = t >> 6, l = t & 63;
  const int wc = w;
  const int l15 = l & 15, lhi = l >> 4;
  const int rowA0 = blockIdx.x * 64;
  const int rowB0 = blockIdx.y * 256;

  f32x4 acc[4][4];
#pragma unroll
  for (int mi = 0; mi < 4; ++mi)
#pragma unroll
    for (int ni = 0; ni < 4; ++ni) acc[mi][ni] = (f32x4){0.f, 0.f, 0.f, 0.f};

  const int srl = w * 8 + (l >> 3);
  const int ss = l & 7;

  const short* aptr[2];
#pragma unroll
  for (int i = 0; i < 2; ++i) {
    const int r = i * 32 + srl;
    aptr[i] = A + (size_t)(rowA0 + r) * K + ((ss ^ (r & 7)) << 3);
  }
  const short* bptr[8];
#pragma unroll
  for (int i = 0; i < 8; ++i) {
    const int r = i * 32 + srl;
    bptr[i] = Bt + (size_t)(rowB0 + r) * K + ((ss ^ (r & 7)) << 3);
  }

  for (int kt = 0; kt < K; kt += BK) {
#pragma unroll
    for (int i = 0; i < 2; ++i) {
      gload_lds16(aptr[i], &Alds[(i * 32 + w * 8) * BK]);
      aptr[i] += BK;
    }
#pragma unroll
    for (int i = 0; i < 8; ++i) {
      gload_lds16(bptr[i], &Blds[(i * 32 + w * 8) * BK]);
      bptr[i] += BK;
    }
    __syncthreads();
    short8 af[4][2], bfr[4][2];
#pragma unroll
    for (int mi = 0; mi < 4; ++mi) {
      const int r = mi * 16 + l15;
#pragma unroll
      for (int kc = 0; kc < 2; ++kc)
        af[mi][kc] = *(const short8*)
            &Alds[r * BK + ((((kc << 2) | lhi) ^ (r & 7)) << 3)];
    }
#pragma unroll
    for (int ni = 0; ni < 4; ++ni) {
      const int r = wc * 64 + ni * 16 + l15;
#pragma unroll
      for (int kc = 0; kc < 2; ++kc)
        bfr[ni][kc] = *(const short8*)
            &Blds[r * BK + ((((kc << 2) | lhi) ^ (r & 7)) << 3)];
    }
#pragma unroll
    for (int mi = 0; mi < 4; ++mi)
#pragma unroll
      for (int ni = 0; ni < 4; ++ni)
#pragma unroll
        for (int kc = 0; kc < 2; ++kc)
          acc[mi][ni] = __builtin_amdgcn_mfma_f32_16x16x32_bf16(
              af[mi][kc], bfr[ni][kc], acc[mi][ni], 0, 0, 0);
    __syncthreads();
  }

  const bool isV = (rowB0 >= 1536);  // block-uniform (1536 % 256 == 0)
  float bv[4];
#pragma unroll
  for (int ni = 0; ni < 4; ++ni) bv[ni] = bias[rowB0 + wc * 64 + ni * 16 + l15];
#pragma unroll
  for (int mi = 0; mi < 4; ++mi) {
#pragma unroll
    for (int ni = 0; ni < 4; ++ni) {
      const int col = rowB0 + wc * 64 + ni * 16 + l15;
#pragma unroll
      for (int i = 0; i < 4; ++i) {
        const int row = rowA0 + mi * 16 + lhi * 4 + i;
        const short s = f2bf(acc[mi][ni][i] + bv[ni]);
        if (!isV) C[(size_t)row * N + col] = s;
        else      Vt[(size_t)(col - 1536) * 8192 + row] = s;
      }
    }
  }
}

// ---------------- fc GEMM: 512-thr 128x256 tile, 8 waves 2Mx4N, BK=64,
// gelu(bf16) epilogue.
__global__ __launch_bounds__(512) void gemm512(const short* __restrict__ A,
                                               const short* __restrict__ Bt,
                                               const float* __restrict__ bias,
                                               short* __restrict__ C,
                                               int N, int K) {
  constexpr int BK = 64;
  __shared__ alignas(16) short Alds[128 * BK];
  __shared__ alignas(16) short Blds[256 * BK];
  const int t = threadIdx.x;
  const int w = t >> 6, l = t & 63;
  const int wr = w >> 2, wc = w & 3;
  const int l15 = l & 15, lhi = l >> 4;
  const int rowA0 = blockIdx.x * 128;
  const int rowB0 = blockIdx.y * 256;

  f32x4 acc[4][4];
#pragma unroll
  for (int mi = 0; mi < 4; ++mi)
#pragma unroll
    for (int ni = 0; ni < 4; ++ni) acc[mi][ni] = (f32x4){0.f, 0.f, 0.f, 0.f};

  const int srl = w * 8 + (l >> 3);
  const int ss = l & 7;

  const short* aptr[2];
#pragma unroll
  for (int i = 0; i < 2; ++i) {
    const int r = i * 64 + srl;
    aptr[i] = A + (size_t)(rowA0 + r) * K + ((ss ^ (r & 7)) << 3);
  }
  const short* bptr[4];
#pragma unroll
  for (int i = 0; i < 4; ++i) {
    const int r = i * 64 + srl;
    bptr[i] = Bt + (size_t)(rowB0 + r) * K + ((ss ^ (r & 7)) << 3);
  }

  for (int kt = 0; kt < K; kt += BK) {
#pragma unroll
    for (int i = 0; i < 2; ++i) {
      gload_lds16(aptr[i], &Alds[(i * 64 + w * 8) * BK]);
      aptr[i] += BK;
    }
#pragma unroll
    for (int i = 0; i < 4; ++i) {
      gload_lds16(bptr[i], &Blds[(i * 64 + w * 8) * BK]);
      bptr[i] += BK;
    }
    __syncthreads();
    short8 af[4][2], bfr[4][2];
#pragma unroll
    for (int mi = 0; mi < 4; ++mi) {
      const int r = wr * 64 + mi * 16 + l15;
#pragma unroll
      for (int kc = 0; kc < 2; ++kc)
        af[mi][kc] = *(const short8*)
            &Alds[r * BK + ((((kc << 2) | lhi) ^ (r & 7)) << 3)];
    }
#pragma unroll
    for (int ni = 0; ni < 4; ++ni) {
      const int r = wc * 64 + ni * 16 + l15;
#pragma unroll
      for (int kc = 0; kc < 2; ++kc)
        bfr[ni][kc] = *(const short8*)
            &Blds[r * BK + ((((kc << 2) | lhi) ^ (r & 7)) << 3)];
    }
#pragma unroll
    for (int mi = 0; mi < 4; ++mi)
#pragma unroll
      for (int ni = 0; ni < 4; ++ni)
#pragma unroll
        for (int kc = 0; kc < 2; ++kc)
          acc[mi][ni] = __builtin_amdgcn_mfma_f32_16x16x32_bf16(
              af[mi][kc], bfr[ni][kc], acc[mi][ni], 0, 0, 0);
    __syncthreads();
  }

  float bv[4];
#pragma unroll
  for (int ni = 0; ni < 4; ++ni) bv[ni] = bias[rowB0 + wc * 64 + ni * 16 + l15];
#pragma unroll
  for (int mi = 0; mi < 4; ++mi) {
#pragma unroll
    for (int ni = 0; ni < 4; ++ni) {
      const int col = rowB0 + wc * 64 + ni * 16 + l15;
#pragma unroll
      for (int i = 0; i < 4; ++i) {
        const int row = rowA0 + wr * 64 + mi * 16 + lhi * 4 + i;
        float v = acc[mi][ni][i] + bv[ni];
        // gelu_new via sigmoid: 0.5x(1+tanh z) = x / (1 + exp(-2z))
        float pz = v * fmaf(0.044715f, v * v, 1.0f);
        float e = __expf(-1.5957691216057308f * pz);
        float r = __builtin_amdgcn_rcpf(1.0f + e);
        C[(size_t)row * N + col] = f2bf(v * r);
      }
    }
  }
}

// ---------------- split-K GEMM for N=768 (proj, mlp): 128x128 tile, BK=64,
// blockIdx.z = K-half. Partial z writes bf16 to C + z*M*N; bias only in z=0.
__global__ __launch_bounds__(256) void gemm_pk(const short* __restrict__ A,
                                               const short* __restrict__ Bt,
                                               const float* __restrict__ bias,
                                               short* __restrict__ C,
                                               int N, int Kfull) {
  constexpr int BK = 64;
  __shared__ alignas(16) short Alds[128 * BK];
  __shared__ alignas(16) short Blds[128 * BK];
  const int t = threadIdx.x;
  const int w = t >> 6, l = t & 63;
  const int wr = w >> 1, wc = w & 1;
  const int l15 = l & 15, lhi = l >> 4;
  const int rowA0 = blockIdx.x * 128;
  const int rowB0 = blockIdx.y * 128;
  const int z = blockIdx.z;
  const int Ks = Kfull >> 1;
  const int koff = z * Ks;
  short* Cp = C + (size_t)z * 8192 * N;

  f32x4 acc[4][4];
#pragma unroll
  for (int mi = 0; mi < 4; ++mi)
#pragma unroll
    for (int ni = 0; ni < 4; ++ni) acc[mi][ni] = (f32x4){0.f, 0.f, 0.f, 0.f};

  const int srl = l >> 3;
  const int ss = l & 7;

  const short* aptr[4];
  const short* bptr[4];
#pragma unroll
  for (int i = 0; i < 4; ++i) {
    const int r = i * 32 + w * 8 + srl;
    aptr[i] = A + (size_t)(rowA0 + r) * Kfull + koff + ((ss ^ (r & 7)) << 3);
    bptr[i] = Bt + (size_t)(rowB0 + r) * Kfull + koff + ((ss ^ (r & 7)) << 3);
  }

  for (int kt = 0; kt < Ks; kt += BK) {
#pragma unroll
    for (int i = 0; i < 4; ++i) {
      gload_lds16(aptr[i], &Alds[i * 2048 + w * 512]);
      gload_lds16(bptr[i], &Blds[i * 2048 + w * 512]);
      aptr[i] += BK; bptr[i] += BK;
    }
    __syncthreads();
    short8 af[4][2], bfr[4][2];
#pragma unroll
    for (int mi = 0; mi < 4; ++mi) {
      const int r = wr * 64 + mi * 16 + l15;
#pragma unroll
      for (int kc = 0; kc < 2; ++kc)
        af[mi][kc] = *(const short8*)
            &Alds[r * 64 + ((((kc << 2) | lhi) ^ (r & 7)) << 3)];
    }
#pragma unroll
    for (int ni = 0; ni < 4; ++ni) {
      const int r = wc * 64 + ni * 16 + l15;
#pragma unroll
      for (int kc = 0; kc < 2; ++kc)
        bfr[ni][kc] = *(const short8*)
            &Blds[r * 64 + ((((kc << 2) | lhi) ^ (r & 7)) << 3)];
    }
#pragma unroll
    for (int mi = 0; mi < 4; ++mi)
#pragma unroll
      for (int ni = 0; ni < 4; ++ni)
#pragma unroll
        for (int kc = 0; kc < 2; ++kc)
          acc[mi][ni] = __builtin_amdgcn_mfma_f32_16x16x32_bf16(
              af[mi][kc], bfr[ni][kc], acc[mi][ni], 0, 0, 0);
    __syncthreads();
  }

  float bv[4];
#pragma unroll
  for (int ni = 0; ni < 4; ++ni)
    bv[ni] = (z == 0) ? bias[rowB0 + wc * 64 + ni * 16 + l15] : 0.f;
#pragma unroll
  for (int mi = 0; mi < 4; ++mi) {
#pragma unroll
    for (int ni = 0; ni < 4; ++ni) {
      const int col = rowB0 + wc * 64 + ni * 16 + l15;
#pragma unroll
      for (int i = 0; i < 4; ++i) {
        const int row = rowA0 + wr * 64 + mi * 16 + lhi * 4 + i;
        Cp[(size_t)row * N + col] = f2bf(acc[mi][ni][i] + bv[ni]);
      }
    }
  }
}

// ---------------- flash attention: block = (qb, head, batch), 4 waves.
// K from qkvb, V^T from Vt, both staged via global_load_lds (swizzled source).
__global__ __launch_bounds__(256) void attn_k(const short* __restrict__ qkv,
                                              const short* __restrict__ Vt,
                                              const float* __restrict__ mask,
                                              short* __restrict__ o) {
  const int qb = blockIdx.x;
  const int hh = blockIdx.y;
  const int b = blockIdx.z;
  const int t = threadIdx.x, w = t >> 6, l = t & 63;
  const int l15 = l & 15, lhi = l >> 4;
  __shared__ alignas(16) short Klds[64 * 64];
  __shared__ alignas(16) short Vlds[64 * 64];   // V^T: row = d, col = kseq

  short8 qa[2];
  {
    const size_t base =
        (size_t)(b * LSEQ + qb * 64 + w * 16 + l15) * 2304 + hh * 64;
    qa[0] = *(const short8*)&qkv[base + lhi * 8];
    qa[1] = *(const short8*)&qkv[base + 32 + lhi * 8];
  }
  __shared__ alignas(16) short Plds[4][16 * 72];
  float mrow[4] = {-1e30f, -1e30f, -1e30f, -1e30f};
  float lrow[4] = {0.f, 0.f, 0.f, 0.f};
  const f32x4 zero4 = {0.f, 0.f, 0.f, 0.f};
  f32x4 oacc[4];
#pragma unroll
  for (int nt = 0; nt < 4; ++nt) oacc[nt] = zero4;

  const int lr = l >> 3, sl = l & 7;  // staging row-in-chunk / 16B slot
  const int nkt = qb + 1;
  for (int kt = 0; kt < nkt; ++kt) {
    __syncthreads();  // previous iteration's K/V/P reads complete
#pragma unroll
    for (int i = 0; i < 2; ++i) {
      const int kr = i * 32 + w * 8 + lr;  // K row (kseq) / V^T row (d)
      gload_lds16(qkv + (size_t)(b * LSEQ + kt * 64 + kr) * 2304 + 768 +
                      hh * 64 + ((sl ^ (kr & 7)) << 3),
                  &Klds[(i * 32 + w * 8) * 64]);
      gload_lds16(Vt + (size_t)(hh * 64 + kr) * 8192 + b * LSEQ + kt * 64 +
                      ((sl ^ (kr & 7)) << 3),
                  &Vlds[(i * 32 + w * 8) * 64]);
    }
    __syncthreads();  // implicit vmcnt(0): tiles resident

    f32x4 s[4];
#pragma unroll
    for (int jt = 0; jt < 4; ++jt) {
      f32x4 z = zero4;
#pragma unroll
      for (int kc = 0; kc < 2; ++kc) {
        const int rowk = jt * 16 + l15;
        short8 kb = *(const short8*)((char*)Klds +
                     ((rowk * 128 + kc * 64 + lhi * 16) ^ ((rowk & 7) << 4)));
        z = __builtin_amdgcn_mfma_f32_16x16x32_bf16(qa[kc], kb, z, 0, 0, 0);
      }
      s[jt] = z;
    }

    float addm[4];
#pragma unroll
    for (int jt = 0; jt < 4; ++jt)
      addm[jt] = (1.0f - mask[b * LSEQ + kt * 64 + jt * 16 + l15]) *
                 -3.402823466e38f;
#pragma unroll
    for (int jt = 0; jt < 4; ++jt) {
      const int colg = kt * 64 + jt * 16 + l15;
#pragma unroll
      for (int i = 0; i < 4; ++i) {
        const int rowg = qb * 64 + w * 16 + lhi * 4 + i;
        float sv = s[jt][i] * 0.125f;
        if (colg > rowg) sv = -10000.0f;
        s[jt][i] = sv + addm[jt];
      }
    }

    float mnew[4], sc[4];
#pragma unroll
    for (int i = 0; i < 4; ++i) {
      float tm = fmaxf(fmaxf(s[0][i], s[1][i]), fmaxf(s[2][i], s[3][i]));
#pragma unroll
      for (int mm = 1; mm < 16; mm <<= 1) tm = fmaxf(tm, __shfl_xor(tm, mm));
      mnew[i] = fmaxf(mrow[i], tm);
      sc[i] = __expf(mrow[i] - mnew[i]);
      mrow[i] = mnew[i];
    }
#pragma unroll
    for (int i = 0; i < 4; ++i) {
      float ts = 0.f;
#pragma unroll
      for (int jt = 0; jt < 4; ++jt) {
        float p = __expf(s[jt][i] - mnew[i]);
        s[jt][i] = p;
        ts += p;
      }
#pragma unroll
      for (int mm = 1; mm < 16; mm <<= 1) ts += __shfl_xor(ts, mm);
      lrow[i] = lrow[i] * sc[i] + ts;
      oacc[0][i] *= sc[i]; oacc[1][i] *= sc[i];
      oacc[2][i] *= sc[i]; oacc[3][i] *= sc[i];
    }

    short* Pw = &Plds[w][0];
#pragma unroll
    for (int jt = 0; jt < 4; ++jt)
#pragma unroll
      for (int i = 0; i < 4; ++i)
        Pw[(lhi * 4 + i) * 72 + jt * 16 + l15] = f2bf(s[jt][i]);
    __syncthreads();
    short8 pa[2];
#pragma unroll
    for (int kc = 0; kc < 2; ++kc)
      pa[kc] = *(const short8*)&Pw[l15 * 72 + kc * 32 + lhi * 8];

#pragma unroll
    for (int nt = 0; nt < 4; ++nt) {
#pragma unroll
      for (int kc = 0; kc < 2; ++kc) {
        const int rown = nt * 16 + l15;
        short8 vb = *(const short8*)((char*)Vlds +
                     ((rown * 128 + kc * 64 + lhi * 16) ^ ((rown & 7) << 4)));
        oacc[nt] = __builtin_amdgcn_mfma_f32_16x16x32_bf16(pa[kc], vb,
                                                           oacc[nt], 0, 0, 0);
      }
    }
  }

#pragma unroll
  for (int i = 0; i < 4; ++i) {
    const size_t row = (size_t)(b * LSEQ + qb * 64 + w * 16 + lhi * 4 + i);
    const float inv = 1.0f / lrow[i];
#pragma unroll
    for (int nt = 0; nt < 4; ++nt)
      o[row * 768 + hh * 64 + nt * 16 + l15] = f2bf(oacc[nt][i] * inv);
  }
}

// =====================================================================
extern "C" void kernel_launch(void* const* d_in, const int* in_sizes, int n_in,
                              void* d_out, int out_size, void* d_ws,
                              size_t ws_size, hipStream_t stream) {
  const float* x    = (const float*)d_in[0];
  const float* mask = (const float*)d_in[1];
  const float* pos  = (const float*)d_in[2];
  const float* caw  = (const float*)d_in[3];
  const float* cab  = (const float*)d_in[4];
  const float* apw  = (const float*)d_in[5];
  const float* apb  = (const float*)d_in[6];
  const float* g1   = (const float*)d_in[7];
  const float* b1   = (const float*)d_in[8];
  const float* fw   = (const float*)d_in[9];
  const float* fb   = (const float*)d_in[10];
  const float* pw   = (const float*)d_in[11];
  const float* pb   = (const float*)d_in[12];
  const float* g2   = (const float*)d_in[13];
  const float* b2   = (const float*)d_in[14];

  char* ws = (char*)d_ws;
  size_t off = 0;
  auto alloc = [&](size_t bytes) {
    size_t o = off;
    off += (bytes + 255) & ~(size_t)255;
    return o;
  };
  short* hbf  = (short*)(ws + alloc(8192ull * 768 * 2));   // residual (bf16)
  short* nbf  = (short*)(ws + alloc(8192ull * 768 * 2));   // LN1 out (bf16)
  short* qkvb = (short*)(ws + alloc(8192ull * 2304 * 2));  // Q,K (V unused)
  short* vT   = (short*)(ws + alloc(768ull * 8192 * 2));   // V transposed
  short* obf  = (short*)(ws + alloc(8192ull * 768 * 2));
  short* aout = (short*)(ws + alloc(2ull * 8192 * 768 * 2));  // split-K partials
  short* gbf  = (short*)(ws + alloc(8192ull * 3072 * 2));
  short* wt_attn = (short*)(ws + alloc(12ull * 768 * 2304 * 2));
  short* wt_proj = (short*)(ws + alloc(12ull * 768 * 768 * 2));
  short* wt_fc   = (short*)(ws + alloc(12ull * 768 * 3072 * 2));
  short* wt_mlp  = (short*)(ws + alloc(12ull * 3072 * 768 * 2));
  short* aout1 = aout + 8192ull * 768;
  (void)ws_size; (void)in_sizes; (void)n_in; (void)out_size;

  wt_transpose<<<dim3(2304 / 32, 768 / 32, 12), 256, 0, stream>>>(caw, wt_attn, 768, 2304);
  wt_transpose<<<dim3(768 / 32, 768 / 32, 12), 256, 0, stream>>>(apw, wt_proj, 768, 768);
  wt_transpose<<<dim3(3072 / 32, 768 / 32, 12), 256, 0, stream>>>(fw, wt_fc, 768, 3072);
  wt_transpose<<<dim3(768 / 32, 3072 / 32, 12), 256, 0, stream>>>(pw, wt_mlp, 3072, 768);

  embed_k<<<8192, 256, 0, stream>>>(x, pos, hbf);

  for (int L = 0; L < 12; ++L) {
    gemm_qkv<<<dim3(128, 9), 256, 0, stream>>>(
        hbf, wt_attn + (size_t)L * 2304 * 768, cab + (size_t)L * 2304, qkvb,
        vT, 2304, 768);
    attn_k<<<dim3(8, 12, 16), 256, 0, stream>>>(qkvb, vT, mask, obf);
    gemm_pk<<<dim3(64, 6, 2), 256, 0, stream>>>(
        obf, wt_proj + (size_t)L * 768 * 768, apb + (size_t)L * 768, aout, 768, 768);
    ln_fused<0><<<2048, 256, 0, stream>>>(hbf, aout, aout1, g1 + (size_t)L * 768,
                                          b1 + (size_t)L * 768, nbf);
    gemm512<<<dim3(64, 12), 512, 0, stream>>>(
        nbf, wt_fc + (size_t)L * 768 * 3072, fb + (size_t)L * 3072, gbf, 3072, 768);
    gemm_pk<<<dim3(64, 6, 2), 256, 0, stream>>>(
        gbf, wt_mlp + (size_t)L * 3072 * 768, pb + (size_t)L * 768, aout, 768, 3072);
    if (L < 11) {
      ln_fused<0><<<2048, 256, 0, stream>>>(nbf, aout, aout1, g2 + (size_t)L * 768,
                                            b2 + (size_t)L * 768, hbf);
    } else {
      ln_fused<1><<<2048, 256, 0, stream>>>(nbf, aout, aout1, g2 + (size_t)L * 768,
                                            b2 + (size_t)L * 768, (float*)d_out);
    }
  }
}